// Round 13
// baseline (374.121 us; speedup 1.0000x reference)
//
#include <hip/hip_runtime.h>
#include <hip/hip_bf16.h>
#include <cstdint>
#include <cstddef>

// ParallelFLAAttention: B=2,N=2048,HID=2048,H=16,KVH=4,D=128,GROUPS=4
// out = softmax_causal(QK^T*s)V @ Wo + 0.01 * GLA(q,k,v)
// I/O f32; internal bf16 MFMA + f32 accum.
// R13 flash: 512 single-phase blocks (set,j,hp) x 512 thr, KVBLK=64 dbuf +
//   Pl[8][16][64] = 81920 B LDS exactly -> 2 blocks/CU = 4 waves/SIMD.
//   R12 post-mortem: round = 4.4K cyc, mostly chain-latency wait at 2
//   waves/SIMD. This split avoids R8's traps: 4 loads/thread (not 8),
//   8-wave barrier groups, different data per co-resident block, dynamic
//   rebalancing over 512 blocks. set=bid&7 aligns sets with XCDs.
//   R12 VALU trims kept (diag peel, cvt_pk pack, setprio, raw exp2).
// R13 rider: 4 weight transposes fused into one launch; 2 V-transposes
//   fused (z) — launch-gap reduction, separately attributable.
// GEMMs: QKV = m97 768-block (3/CU); final = 256x128 depth-2 pipeline.
// FLA: factorized chunk form (T=32), all MFMA; prefix depth-2 unroll.

typedef __attribute__((ext_vector_type(4))) float f32x4;
typedef __attribute__((ext_vector_type(2))) float f32x2;
typedef __attribute__((ext_vector_type(8))) short s16x8;
typedef unsigned short u16;
typedef unsigned int u32;

__device__ __forceinline__ float bfu2f(u16 u) {
  union { unsigned int i; float f; } x; x.i = ((unsigned int)u) << 16; return x.f;
}
__device__ __forceinline__ u16 f2bfu(float f) {
  union { float f; unsigned int i; } x; x.f = f;
  unsigned int r = x.i + 0x7fffu + ((x.i >> 16) & 1u);
  return (u16)(r >> 16);
}
__device__ __forceinline__ void bf8_to_f(s16x8 v, float* o) {
  union { s16x8 v; u16 u[8]; } x; x.v = v;
#pragma unroll
  for (int j = 0; j < 8; j++) o[j] = bfu2f(x.u[j]);
}
__device__ __forceinline__ s16x8 pack_bf8(f32x4 lo, f32x4 hi) {
  union { s16x8 v; u16 u[8]; } x;
#pragma unroll
  for (int j = 0; j < 4; j++) { x.u[j] = f2bfu(lo[j]); x.u[4 + j] = f2bfu(hi[j]); }
  return x.v;
}
__device__ __forceinline__ void gload_lds16(const u16* g, u16* l) {
  __builtin_amdgcn_global_load_lds(
      (__attribute__((address_space(1))) void*)(g),
      (__attribute__((address_space(3))) void*)(l), 16, 0, 0);
}

// ---------------------------------------------------------------- utility
__global__ __launch_bounds__(256) void f32_to_bf16(
    const float* __restrict__ src, u16* __restrict__ dst, int n8) {
  const int i = blockIdx.x * 256 + threadIdx.x;
  if (i < n8) {
    f32x4 a = *(const f32x4*)(src + (size_t)i * 8);
    f32x4 b = *(const f32x4*)(src + (size_t)i * 8 + 4);
    *(s16x8*)(dst + (size_t)i * 8) = pack_bf8(a, b);
  }
}

// ---------------------------------------------------------------- fused weight transposes (f32 -> bf16^T), one launch
// segments: [0,4096) Wq 2048x2048; [4096,5120) Wk 2048x512;
// [5120,6144) Wv 2048x512; [6144,10240) Wo 2048x2048.
__global__ __launch_bounds__(256) void transpose_w4(
    const float* __restrict__ Wq, const float* __restrict__ Wk,
    const float* __restrict__ Wv, const float* __restrict__ Wo,
    u16* __restrict__ WqT, u16* __restrict__ WkT,
    u16* __restrict__ WvT, u16* __restrict__ WoT) {
  __shared__ u16 tile[32][33];
  const int bid = blockIdx.x;
  const float* src; u16* dst; int R, C, bx, by;
  if (bid < 4096)      { src = Wq; dst = WqT; R = 2048; C = 2048; bx = (bid & 63) * 32; by = (bid >> 6) * 32; }
  else if (bid < 5120) { const int v = bid - 4096; src = Wk; dst = WkT; R = 2048; C = 512;  bx = (v & 15) * 32; by = (v >> 4) * 32; }
  else if (bid < 6144) { const int v = bid - 5120; src = Wv; dst = WvT; R = 2048; C = 512;  bx = (v & 15) * 32; by = (v >> 4) * 32; }
  else                 { const int v = bid - 6144; src = Wo; dst = WoT; R = 2048; C = 2048; bx = (v & 63) * 32; by = (v >> 6) * 32; }
  const int tx = threadIdx.x & 31, ty = threadIdx.x >> 5;  // 32 x 8
#pragma unroll
  for (int i = 0; i < 32; i += 8)
    tile[ty + i][tx] = f2bfu(src[(size_t)(by + ty + i) * C + bx + tx]);
  __syncthreads();
#pragma unroll
  for (int i = 0; i < 32; i += 8)
    dst[(size_t)(bx + ty + i) * R + by + tx] = tile[tx][ty + i];
}

// V transpose (bf16), both batches in one launch via blockIdx.z
__global__ __launch_bounds__(256) void transpose_bf16v(
    const u16* __restrict__ src0, u16* __restrict__ dst0) {
  __shared__ u16 tile[32][33];
  const int R = 2048, C = 512;
  const u16* src = src0 + (size_t)blockIdx.z * 2048 * 512;
  u16* dst = dst0 + (size_t)blockIdx.z * 512 * 2048;
  const int bx = blockIdx.x * 32, by = blockIdx.y * 32;
  const int tx = threadIdx.x & 31, ty = threadIdx.x >> 5;
#pragma unroll
  for (int i = 0; i < 32; i += 8)
    tile[ty + i][tx] = src[(size_t)(by + ty + i) * C + bx + tx];
  __syncthreads();
#pragma unroll
  for (int i = 0; i < 32; i += 8)
    dst[(size_t)(bx + ty + i) * R + by + tx] = tile[tx][ty + i];
}

// ---------------------------------------------------------------- merged QKV projection GEMM (m97 structure)
// grid (24, 32): bx<16 -> Q col-block; bx in [16,20) -> K; [20,24) -> V.
// Identical per-block FLOPs; 768 blocks = 3/CU (implicit cross-block
// wave overlap, m114 — beats explicit 2-phase here, R6 post-mortem).
__global__ __launch_bounds__(256) void gemm_qkv(
    const u16* __restrict__ A, const u16* __restrict__ WqT, const u16* __restrict__ WkT,
    const u16* __restrict__ WvT, u16* __restrict__ Qo, u16* __restrict__ Ko,
    u16* __restrict__ Vo) {
  __shared__ u16 Al[128 * 32];
  __shared__ u16 Bl[128 * 32];
  const int bx = blockIdx.x;
  const u16* Bt; u16* Cb; int n0, Nst;
  if (bx < 16)      { Bt = WqT; Cb = Qo; n0 = bx * 128;        Nst = 2048; }
  else if (bx < 20) { Bt = WkT; Cb = Ko; n0 = (bx - 16) * 128; Nst = 512; }
  else              { Bt = WvT; Cb = Vo; n0 = (bx - 20) * 128; Nst = 512; }
  const int K = 2048;
  const int m0 = blockIdx.y * 128;
  const int t = threadIdx.x, w = t >> 6, l = t & 63, lm = l & 15, lq = l >> 4;
  const int wr = w >> 1, wc = w & 1;
  const f32x4 z4 = {0.f, 0.f, 0.f, 0.f};
  f32x4 acc[4][4];
#pragma unroll
  for (int i = 0; i < 4; i++)
#pragma unroll
    for (int j = 0; j < 4; j++) acc[i][j] = z4;
  const int srow = l >> 2, scol = (l & 3) * 8;
  const u16* Ag = A + (size_t)(m0 + w * 32 + srow) * K + scol;
  const u16* Bg = Bt + (size_t)(n0 + w * 32 + srow) * K + scol;
  u16* Alw = &Al[(w * 32) * 32];
  u16* Blw = &Bl[(w * 32) * 32];
  for (int kk = 0; kk < K; kk += 32) {
    gload_lds16(Ag + kk, Alw);
    gload_lds16(Ag + (size_t)16 * K + kk, Alw + 16 * 32);
    gload_lds16(Bg + kk, Blw);
    gload_lds16(Bg + (size_t)16 * K + kk, Blw + 16 * 32);
    __syncthreads();
    s16x8 af[4], bfr[4];
#pragma unroll
    for (int sm = 0; sm < 4; sm++) af[sm] = *(const s16x8*)&Al[(wr * 64 + sm * 16 + lm) * 32 + lq * 8];
#pragma unroll
    for (int sn = 0; sn < 4; sn++) bfr[sn] = *(const s16x8*)&Bl[(wc * 64 + sn * 16 + lm) * 32 + lq * 8];
#pragma unroll
    for (int sm = 0; sm < 4; sm++)
#pragma unroll
      for (int sn = 0; sn < 4; sn++)
        acc[sm][sn] = __builtin_amdgcn_mfma_f32_16x16x32_bf16(af[sm], bfr[sn], acc[sm][sn], 0, 0, 0);
    __syncthreads();
  }
#pragma unroll
  for (int sm = 0; sm < 4; sm++)
#pragma unroll
    for (int sn = 0; sn < 4; sn++)
#pragma unroll
      for (int r = 0; r < 4; r++) {
        const int row = m0 + wr * 64 + sm * 16 + lq * 4 + r;
        const int col = n0 + wc * 64 + sn * 16 + lm;
        Cb[(size_t)row * Nst + col] = f2bfu(acc[sm][sn][r]);
      }
}

// ---------------------------------------------------------------- final GEMM: 256x128 tile, depth-2 pipeline
__global__ __launch_bounds__(512) void gemm_out2(
    const u16* __restrict__ A, const u16* __restrict__ Bt, float* __restrict__ Cf,
    const u16* __restrict__ addsrc) {
  __shared__ u16 Abuf[3 * 16384];
  __shared__ u16 Bbuf[3 * 8192];
  int f = blockIdx.y * 16 + blockIdx.x;   // 0..255
  f = (f & 7) * 32 + (f >> 3);            // bijective XCD swizzle (256%8==0)
  const int by = f >> 4, bx = f & 15;
  const int m0 = by * 256, n0 = bx * 128;
  const int K = 2048, Nst = 2048;
  const int t = threadIdx.x, w = t >> 6, l = t & 63, lm = l & 15, lq = l >> 4;
  const int wr = w >> 1, wc = w & 1;
  const int tr = t >> 3, tc8 = (t & 7) * 8;   // staging row-in-64 / col-u16 base
  const f32x4 z4 = {0.f, 0.f, 0.f, 0.f};
  f32x4 acc[4][4];
#pragma unroll
  for (int i = 0; i < 4; i++)
#pragma unroll
    for (int j = 0; j < 4; j++) acc[i][j] = z4;
  const u16* Ag = A + (size_t)m0 * K;
  const u16* Bg = Bt + (size_t)n0 * K;
  auto stage = [&](int kt, int bufi) {
#pragma unroll
    for (int i = 0; i < 4; i++) {
      const int row = i * 64 + tr;
      const int col = tc8 ^ ((row & 7) << 3);  // pre-swizzled source (u16)
      gload_lds16(Ag + (size_t)row * K + kt * 64 + col,
                  Abuf + bufi * 16384 + i * 4096 + w * 512);
    }
#pragma unroll
    for (int i = 0; i < 2; i++) {
      const int row = i * 64 + tr;
      const int col = tc8 ^ ((row & 7) << 3);
      gload_lds16(Bg + (size_t)row * K + kt * 64 + col,
                  Bbuf + bufi * 8192 + i * 4096 + w * 512);
    }
  };
  const int nt = K >> 6;  // 32
  stage(0, 0);
  stage(1, 1);
  int cur = 0;
#pragma unroll 1
  for (int kt = 0; kt < nt; kt++) {
    if (kt + 2 < nt) {
      int nb = cur + 2; if (nb >= 3) nb -= 3;
      stage(kt + 2, nb);
      asm volatile("s_waitcnt vmcnt(12)" ::: "memory");  // kt done; kt+1,kt+2 in flight
    } else if (kt + 1 < nt) {
      asm volatile("s_waitcnt vmcnt(6)" ::: "memory");   // kt done; kt+1 in flight
    } else {
      asm volatile("s_waitcnt vmcnt(0)" ::: "memory");
    }
    __builtin_amdgcn_s_barrier();
    const u16* Ab = Abuf + cur * 16384;
    const u16* Bb = Bbuf + cur * 8192;
    s16x8 af[4][2], bff[4][2];
#pragma unroll
    for (int sm = 0; sm < 4; sm++) {
      const int row = wr * 64 + sm * 16 + lm;
#pragma unroll
      for (int kk = 0; kk < 2; kk++)
        af[sm][kk] = *(const s16x8*)&Ab[row * 64 +
            ((((kk << 6) | (lq << 4)) ^ ((row & 7) << 4)) >> 1)];
    }
#pragma unroll
    for (int sn = 0; sn < 4; sn++) {
      const int row = wc * 64 + sn * 16 + lm;
#pragma unroll
      for (int kk = 0; kk < 2; kk++)
        bff[sn][kk] = *(const s16x8*)&Bb[row * 64 +
            ((((kk << 6) | (lq << 4)) ^ ((row & 7) << 4)) >> 1)];
    }
#pragma unroll
    for (int kk = 0; kk < 2; kk++)
#pragma unroll
      for (int sm = 0; sm < 4; sm++)
#pragma unroll
        for (int sn = 0; sn < 4; sn++)
          acc[sm][sn] = __builtin_amdgcn_mfma_f32_16x16x32_bf16(
              af[sm][kk], bff[sn][kk], acc[sm][sn], 0, 0, 0);
    asm volatile("s_waitcnt lgkmcnt(0)" ::: "memory");
    __builtin_amdgcn_s_barrier();
    cur = (cur == 2) ? 0 : cur + 1;
  }
#pragma unroll
  for (int sm = 0; sm < 4; sm++)
#pragma unroll
    for (int sn = 0; sn < 4; sn++)
#pragma unroll
      for (int r = 0; r < 4; r++) {
        const int row = m0 + wr * 64 + sm * 16 + lq * 4 + r;
        const int col = n0 + wc * 64 + sn * 16 + lm;
        float v = acc[sm][sn][r] + 0.01f * bfu2f(addsrc[(size_t)row * Nst + col]);
        Cf[(size_t)row * Nst + col] = v;
      }
}

// ---------------------------------------------------------------- flash attention: single-phase, 2 blocks/CU
// 512 blocks x 512 threads. bid -> set=bid&7 (b*4+kvh) [aligns with XCD
// round-robin: each XCD's L2 holds one set's 1MB K/V], rest=bid>>3:
// j = rest>>1 (0..31), hp = rest&1. Wave w: head h = kvh*4+hp*2+(w&1);
// chunk c = 2j+((w>>1)&1); row-half mh = w>>2. kt = 0..j (single phase;
// 512 blocks dynamically rebalance over 256 CUs). KVBLK=64 dbuf + packed
// Pl[8][16][64] = 81920 B LDS -> 2 blocks/CU = 4 waves/SIMD.
__global__ __launch_bounds__(512) void flash_attn_wave(
    const u16* __restrict__ Q, const u16* __restrict__ Kx,
    const u16* __restrict__ Vt, u16* __restrict__ AO) {
  __shared__ u16 Klds[2][64 * 128];   // [buf][key][d], 2x16 KB, swizzled contents
  __shared__ u16 Vlds[2][128 * 64];   // [buf][d][key], 2x16 KB, swizzled contents
  __shared__ u16 Pl[8][16][64];       // per-wave P tile, 16384 B (no pad)
  const int bid = blockIdx.x;
  const int set = bid & 7;
  const int b = set >> 2, kvh = set & 3;
  const int rest = bid >> 3;
  const int j = rest >> 1, hp = rest & 1;
  const int t = threadIdx.x, w = t >> 6, l = t & 63, lm = l & 15, lq = l >> 4;
  const int h = kvh * 4 + hp * 2 + (w & 1);
  const int cs = (w >> 1) & 1, mh = w >> 2;
  const float scale2 = 0.127517827f;   // (1/sqrt(128)) * log2(e)
  const u16* Kbase = Kx + (size_t)(b * 2048) * 512 + kvh * 128;
  const u16* Vbase = Vt + (size_t)(b * 512 + kvh * 128) * 2048;
  const f32x4 z4 = {0.f, 0.f, 0.f, 0.f};

  auto stage = [&](int kt, int bufi) {
    const int key0 = kt * 64;
#pragma unroll
    for (int r = 0; r < 2; r++) {
      const int row = r * 32 + w * 4 + (l >> 4);     // key row 0..63
      const int scb = ((l & 15) * 16) ^ ((row & 7) << 4);
      gload_lds16(Kbase + (size_t)(key0 + row) * 512 + (scb >> 1),
                  &Klds[bufi][r * 4096 + w * 512]);
    }
#pragma unroll
    for (int r = 0; r < 2; r++) {
      const int row = r * 64 + w * 8 + (l >> 3);     // d row 0..127
      const int scb = ((l & 7) * 16) ^ ((row & 7) << 4);
      gload_lds16(Vbase + (size_t)row * 2048 + key0 + (scb >> 1),
                  &Vlds[bufi][r * 4096 + w * 512]);
    }
  };

  const int c = 2 * j + cs;
  const int base = c * 32;
  int cur = 0;
  stage(0, 0);
  // Q fragment for this wave's 16 rows
  s16x8 qf[4];
#pragma unroll
  for (int kk = 0; kk < 4; kk++)
    qf[kk] = *(const s16x8*)(Q + ((size_t)(b * 2048 + base + mh * 16 + lm)) * 2048 +
                             h * 128 + kk * 32 + lq * 8);
  f32x4 oacc[8];
#pragma unroll
  for (int e = 0; e < 8; e++) oacc[e] = z4;
  float lsum[4] = {0.f, 0.f, 0.f, 0.f};
#pragma unroll 1
  for (int kt = 0; kt <= j; kt++) {
    const int key0 = kt * 64;
    if (kt < j) {
      stage(kt + 1, cur ^ 1);
      asm volatile("s_waitcnt vmcnt(4)" ::: "memory");
    } else {
      asm volatile("s_waitcnt vmcnt(0)" ::: "memory");
    }
    __builtin_amdgcn_s_barrier();
    const char* KB = (const char*)&Klds[cur][0];
    const char* VB = (const char*)&Vlds[cur][0];
    // ---- QK^T for this wave's 16 rows x 64 keys
    s16x8 kf[4][4];
#pragma unroll
    for (int nst = 0; nst < 4; nst++)
#pragma unroll
      for (int kk = 0; kk < 4; kk++) {
        const int row = nst * 16 + lm;
        const int cb = (kk * 64 + lq * 16) ^ ((row & 7) << 4);
        kf[nst][kk] = *(const s16x8*)(KB + row * 256 + cb);
      }
    f32x4 sacc[4];
#pragma unroll
    for (int i = 0; i < 4; i++) sacc[i] = z4;
    __builtin_amdgcn_s_setprio(1);
#pragma unroll
    for (int nst = 0; nst < 4; nst++)
#pragma unroll
      for (int kk = 0; kk < 4; kk++)
        sacc[nst] = __builtin_amdgcn_mfma_f32_16x16x32_bf16(
            qf[kk], kf[nst][kk], sacc[nst], 0, 0, 0);
    __builtin_amdgcn_s_setprio(0);
    // exp (all tiles); mask only on the diagonal tile (uniform branch)
    float pv[4][4];
#pragma unroll
    for (int r = 0; r < 4; r++)
#pragma unroll
      for (int nst = 0; nst < 4; nst++)
        pv[r][nst] = __builtin_amdgcn_exp2f(sacc[nst][r] * scale2);
    if (kt == j) {
#pragma unroll
      for (int r = 0; r < 4; r++) {
        const int qrow = base + mh * 16 + lq * 4 + r;
#pragma unroll
        for (int nst = 0; nst < 4; nst++)
          if (key0 + nst * 16 + lm > qrow) pv[r][nst] = 0.f;
      }
    }
#pragma unroll
    for (int r = 0; r < 4; r++) {
      lsum[r] += (pv[r][0] + pv[r][1]) + (pv[r][2] + pv[r][3]);
      u32 p01, p23;
      asm("v_cvt_pk_bf16_f32 %0, %1, %2" : "=v"(p01) : "v"(pv[r][0]), "v"(pv[r][1]));
      asm("v_cvt_pk_bf16_f32 %0, %1, %2" : "=v"(p23) : "v"(pv[r][2]), "v"(pv[r][3]));
      u16* prow = &Pl[w][lq * 4 + r][lm];
      prow[0]  = (u16)p01;
      prow[16] = (u16)(p01 >> 16);
      prow[32] = (u16)p23;
      prow[48] = (u16)(p23 >> 16);
    }
    // ---- PV
    s16x8 vf[8][2];
#pragma unroll
    for (int et = 0; et < 8; et++)
#pragma unroll
      for (int kc = 0; kc < 2; kc++) {
        const int row = et * 16 + lm;
        const int cb = (kc * 64 + lq * 16) ^ ((row & 7) << 4);
        vf[et][kc] = *(const s16x8*)(VB + row * 128 + cb);
      }
    s16x8 pf[2];
#pragma unroll
    for (int kc = 0; kc < 2; kc++)
      pf[kc] = *(const s16x8*)&Pl[w][lm][kc * 32 + lq * 8];
    __builtin_amdgcn_s_setprio(1);
#pragma unroll
    for (int et = 0; et < 8; et++)
#pragma unroll
      for (int kc = 0; kc < 2; kc++)
        oacc[et] = __builtin_amdgcn_mfma_f32_16x16x32_bf16(
            pf[kc], vf[et][kc], oacc[et], 0, 0, 0);
    __builtin_amdgcn_s_setprio(0);
    asm volatile("s_waitcnt lgkmcnt(0)" ::: "memory");
    __builtin_amdgcn_s_barrier();
    cur ^= 1;
  }
  // ---- normalize + store
#pragma unroll
  for (int r = 0; r < 4; r++) {
#pragma unroll
    for (int off = 1; off < 16; off <<= 1)
      lsum[r] += __shfl_xor(lsum[r], off, 64);
  }
#pragma unroll
  for (int r = 0; r < 4; r++) {
    const float inv = 1.f / lsum[r];
    const int row = base + mh * 16 + lq * 4 + r;
    u16* op = AO + ((size_t)(b * 2048 + row)) * 2048 + h * 128;
#pragma unroll
    for (int et = 0; et < 8; et++) op[et * 16 + lm] = f2bfu(oacc[et][r] * inv);
  }
}

// ---------------------------------------------------------------- FLA: per-32-chunk gates + contribution
__global__ __launch_bounds__(256) void fla_contrib32(
    const u16* __restrict__ Kx, const u16* __restrict__ Vt,
    u16* __restrict__ Gg, u16* __restrict__ Ktg, u16* __restrict__ MT,
    float* __restrict__ Lam) {
  __shared__ float gl[32][132];
  __shared__ float kl[32][132];
  __shared__ float ktl[32][132];
  __shared__ u16 khT[128][40];
  const int c = blockIdx.x, kvh = blockIdx.y, b = blockIdx.z;
  const int bk = b * 4 + kvh;
  const int t = threadIdx.x;
  const size_t cb = (size_t)bk * 64 + c;
  {
    const int r = t >> 3, c0 = (t & 7) * 16;
    const u16* kp = Kx + ((size_t)(b * 2048 + c * 32 + r)) * 512 + kvh * 128 + c0;
#pragma unroll
    for (int i = 0; i < 2; i++) {
      float kv[8];
      bf8_to_f(*(const s16x8*)(kp + i * 8), kv);
#pragma unroll
      for (int j = 0; j < 8; j++) {
        kl[r][c0 + i * 8 + j] = kv[j];
        gl[r][c0 + i * 8 + j] = 1.f / (1.f + __expf(-kv[j]));
      }
    }
  }
  __syncthreads();
  if (t < 128) {  // one thread per d: cumprod + ktilde + khat^T
    float G = 1.f;
#pragma unroll
    for (int s = 0; s < 32; s++) {
      G *= gl[s][t];
      gl[s][t] = G;
      ktl[s][t] = kl[s][t] / G;
    }
    Lam[cb * 128 + t] = G;
    const float lam = G;
#pragma unroll
    for (int s = 0; s < 32; s++) khT[t][s] = f2bfu(ktl[s][t] * lam);
  }
  __syncthreads();
  {
    const int r = t >> 3, c0 = (t & 7) * 16;
    u16* gp = Gg + cb * 4096 + r * 128 + c0;
    u16* kp = Ktg + cb * 4096 + r * 128 + c0;
#pragma unroll
    for (int i = 0; i < 2; i++) {
      f32x4 a = *(f32x4*)&gl[r][c0 + i * 8];
      f32x4 b2 = *(f32x4*)&gl[r][c0 + i * 8 + 4];
      *(s16x8*)(gp + i * 8) = pack_bf8(a, b2);
      a = *(f32x4*)&ktl[r][c0 + i * 8];
      b2 = *(f32x4*)&ktl[r][c0 + i * 8 + 4];
      *(s16x8*)(kp + i * 8) = pack_bf8(a, b2);
    }
  }
  const int w = t >> 6, l = t & 63, lm = l & 15, lq = l >> 4;
  const f32x4 z4 = {0.f, 0.f, 0.f, 0.f};
  f32x4 macc[2][8];
#pragma unroll
  for (int ei = 0; ei < 2; ei++)
#pragma unroll
    for (int dt = 0; dt < 8; dt++) macc[ei][dt] = z4;
  s16x8 vtf[2];
#pragma unroll
  for (int ei = 0; ei < 2; ei++) {
    const int et = w * 2 + ei;
    vtf[ei] = *(const s16x8*)(Vt + ((size_t)(b * 512 + kvh * 128 + et * 16 + lm)) * 2048 +
                              c * 32 + lq * 8);
  }
#pragma unroll
  for (int dt = 0; dt < 8; dt++) {
    s16x8 kf = *(const s16x8*)&khT[dt * 16 + lm][lq * 8];
#pragma unroll
    for (int ei = 0; ei < 2; ei++)
      macc[ei][dt] = __builtin_amdgcn_mfma_f32_16x16x32_bf16(vtf[ei], kf, macc[ei][dt], 0, 0, 0);
  }
  u16* mp = MT + cb * 16384;
#pragma unroll
  for (int ei = 0; ei < 2; ei++)
#pragma unroll
    for (int dt = 0; dt < 8; dt++)
#pragma unroll
      for (int r = 0; r < 4; r++)
        mp[(size_t)((w * 2 + ei) * 16 + lq * 4 + r) * 128 + dt * 16 + lm] =
            f2bfu(macc[ei][dt][r]);
}

// ---------------------------------------------------------------- FLA prefix: parallel over (bk,e,d), depth-2 prefetch
__global__ __launch_bounds__(256) void fla_prefix32(
    const u16* __restrict__ MT, const float* __restrict__ Lam, u16* __restrict__ SwsT) {
  const int eg = blockIdx.x, bk = blockIdx.y;
  const int t = threadIdx.x;
  const int e = eg * 4 + (t >> 6), d0 = (t & 63) * 2;
  const size_t cb0 = (size_t)bk * 64;
  const u16* mp = MT + cb0 * 16384 + e * 128 + d0;
  const float* lp = Lam + cb0 * 128 + d0;
  u16* sp = SwsT + cb0 * 16384 + e * 128 + d0;
  float s0 = 0.f, s1 = 0.f;
  u32 ma = *(const u32*)mp;
  u32 mb = *(const u32*)(mp + 16384);
  f32x2 la = *(const f32x2*)lp;
  f32x2 lb = *(const f32x2*)(lp + 128);
#pragma unroll 1
  for (int c = 0; c < 64; c += 2) {
    u32 na = 0, nb = 0;
    f32x2 nla = {0.f, 0.f}, nlb = {0.f, 0.f};
    if (c + 2 < 64) {
      na = *(const u32*)(mp + (size_t)(c + 2) * 16384);
      nla = *(const f32x2*)(lp + (size_t)(c + 2) * 128);
      nb = *(const u32*)(mp + (size_t)(c + 3) * 16384);
      nlb = *(const f32x2*)(lp + (size_t)(c + 3) * 128);
    }
    *(u32*)(sp + (size_t)c * 16384) = (u32)f2bfu(s0) | ((u32)f2bfu(s1) << 16);
    s0 = s0 * la[0] + bfu2f((u16)(ma & 0xffffu));
    s1 = s1 * la[1] + bfu2f((u16)(ma >> 16));
    *(u32*)(sp + (size_t)(c + 1) * 16384) = (u32)f2bfu(s0) | ((u32)f2bfu(s1) << 16);
    s0 = s0 * lb[0] + bfu2f((u16)(mb & 0xffffu));
    s1 = s1 * lb[1] + bfu2f((u16)(mb >> 16));
    ma = na; mb = nb; la = nla; lb = nlb;
  }
}

// ---------------------------------------------------------------- FLA output: O = scale*(q~ S0 + tril(q~ k~^T) v)
__global__ __launch_bounds__(256) void fla_output_mfma(
    const u16* __restrict__ Q, const u16* __restrict__ Gg, const u16* __restrict__ Ktg,
    const u16* __restrict__ SwsT, const u16* __restrict__ Vt, u16* __restrict__ Fla) {
  __shared__ u16 Pl[4][2][16][40];
  const int c = blockIdx.x, h = blockIdx.y, b = blockIdx.z;
  const int kvh = h >> 2, bk = b * 4 + kvh;
  const int t = threadIdx.x, w = t >> 6, l = t & 63, lm = l & 15, lq = l >> 4;
  const float scale = 0.0883883476483184f;
  const size_t cb = (size_t)bk * 64 + c;
  const f32x4 z4 = {0.f, 0.f, 0.f, 0.f};
  s16x8 qgf[2][4];
#pragma unroll
  for (int m = 0; m < 2; m++)
#pragma unroll
    for (int kk = 0; kk < 4; kk++) {
      float qv[8], gv[8];
      bf8_to_f(*(const s16x8*)(Q + ((size_t)(b * 2048 + c * 32 + m * 16 + lm)) * 2048 +
                               h * 128 + kk * 32 + lq * 8), qv);
      bf8_to_f(*(const s16x8*)(Gg + cb * 4096 + (m * 16 + lm) * 128 + kk * 32 + lq * 8), gv);
      f32x4 a, b2;
#pragma unroll
      for (int j = 0; j < 4; j++) { a[j] = qv[j] * gv[j]; b2[j] = qv[4 + j] * gv[4 + j]; }
      qgf[m][kk] = pack_bf8(a, b2);
    }
  f32x4 sacc[2][2];
#pragma unroll
  for (int m = 0; m < 2; m++)
#pragma unroll
    for (int st = 0; st < 2; st++) sacc[m][st] = z4;
#pragma unroll
  for (int st = 0; st < 2; st++)
#pragma unroll
    for (int kk = 0; kk < 4; kk++) {
      s16x8 ktf = *(const s16x8*)(Ktg + cb * 4096 + (st * 16 + lm) * 128 + kk * 32 + lq * 8);
#pragma unroll
      for (int m = 0; m < 2; m++)
        sacc[m][st] = __builtin_amdgcn_mfma_f32_16x16x32_bf16(qgf[m][kk], ktf, sacc[m][st], 0, 0, 0);
    }
#pragma unroll
  for (int m = 0; m < 2; m++)
#pragma unroll
    for (int st = 0; st < 2; st++)
#pragma unroll
      for (int r = 0; r < 4; r++) {
        const int trow = m * 16 + lq * 4 + r;
        const int scol = st * 16 + lm;
        Pl[w][m][lq * 4 + r][st * 16 + lm] = f2bfu(scol <= trow ? sacc[m][st][r] : 0.f);
      }
  s16x8 pf[2];
#pragma unroll
  for (int m = 0; m < 2; m++) pf[m] = *(const s16x8*)&Pl[w][m][lm][lq * 8];
  f32x4 oacc[2][2];
#pragma unroll
  for (int m = 0; m < 2; m++)
#pragma unroll
    for (int ei = 0; ei < 2; ei++) oacc[m][ei] = z4;
#pragma unroll
  for (int ei = 0; ei < 2; ei++) {
    const int et = w * 2 + ei;
    s16x8 vtf = *(const s16x8*)(Vt + ((size_t)(b * 512 + kvh * 128 + et * 16 + lm)) * 2048 +
                                c * 32 + lq * 8);
#pragma unroll
    for (int m = 0; m < 2; m++)
      oacc[m][ei] = __builtin_amdgcn_mfma_f32_16x16x32_bf16(pf[m], vtf, oacc[m][ei], 0, 0, 0);
#pragma unroll
    for (int kk = 0; kk < 4; kk++) {
      s16x8 s0f = *(const s16x8*)(SwsT + cb * 16384 + (et * 16 + lm) * 128 + kk * 32 + lq * 8);
#pragma unroll
      for (int m = 0; m < 2; m++)
        oacc[m][ei] = __builtin_amdgcn_mfma_f32_16x16x32_bf16(qgf[m][kk], s0f, oacc[m][ei], 0, 0, 0);
    }
  }
#pragma unroll
  for (int m = 0; m < 2; m++)
#pragma unroll
    for (int ei = 0; ei < 2; ei++)
#pragma unroll
      for (int r = 0; r < 4; r++)
        Fla[((size_t)(b * 2048 + c * 32 + m * 16 + lq * 4 + r)) * 2048 + h * 128 +
            (w * 2 + ei) * 16 + lm] = f2bfu(scale * oacc[m][ei][r]);
}

// ---------------------------------------------------------------- launch
extern "C" void kernel_launch(void* const* d_in, const int* in_sizes, int n_in,
                              void* d_out, int out_size, void* d_ws, size_t ws_size,
                              hipStream_t stream) {
  const float* X  = (const float*)d_in[0];
  const float* Wq = (const float*)d_in[1];
  const float* Wk = (const float*)d_in[2];
  const float* Wv = (const float*)d_in[3];
  const float* Wo = (const float*)d_in[4];
  float* out = (float*)d_out;

  char* ws = (char*)d_ws;
  size_t off = 0;
  auto alloc = [&](size_t bytes) { void* p = ws + off; off += (bytes + 255) & ~(size_t)255; return p; };
  u16* WoT = (u16*)alloc(2048ull * 2048 * 2);     // 8 MB, live to end
  u16* Qb  = (u16*)alloc(4096ull * 2048 * 2);     // 16 MB
  u16* Kb  = (u16*)alloc(4096ull * 512 * 2);      // 4 MB
  u16* Vb  = (u16*)alloc(4096ull * 512 * 2);      // 4 MB
  u16* Vtb = (u16*)alloc(2ull * 512 * 2048 * 2);  // 4 MB
  u16* Fla = (u16*)alloc(4096ull * 2048 * 2);     // 16 MB
  // time-shared 16 MB region: Xb (until KV proj) -> MT (contrib..prefix) -> AO (flash..end)
  u16* SH16 = (u16*)alloc(4096ull * 2048 * 2);
  u16* Xb = SH16;
  u16* MT = SH16;
  u16* AO = SH16;
  // time-shared scratch: WqT/WkT/WvT early; G/ktilde/SwsT/Lam after projections
  char* BIG = (char*)alloc(26ull * 1024 * 1024);
  u16* WqT = (u16*)BIG;                            // 8 MB
  u16* WkT = (u16*)(BIG + 8ull * 1024 * 1024);     // 2 MB
  u16* WvT = (u16*)(BIG + 10ull * 1024 * 1024);    // 2 MB
  u16* Gg   = (u16*)BIG;                           // 4 MB
  u16* Ktg  = (u16*)(BIG + 4194304ull);            // 4 MB
  u16* SwsT = (u16*)(BIG + 8388608ull);            // 16.78 MB
  float* Lam = (float*)(BIG + 8388608ull + 16777216ull);  // 256 KB
  (void)ws_size; (void)in_sizes; (void)n_in; (void)out_size;

  dim3 blk(256);
  f32_to_bf16<<<dim3(4096), blk, 0, stream>>>(X, Xb, 4096 * 2048 / 8);
  transpose_w4<<<dim3(10240), blk, 0, stream>>>(Wq, Wk, Wv, Wo, WqT, WkT, WvT, WoT);

  gemm_qkv<<<dim3(24, 32), blk, 0, stream>>>(Xb, WqT, WkT, WvT, Qb, Kb, Vb);

  transpose_bf16v<<<dim3(16, 64, 2), blk, 0, stream>>>(Vb, Vtb);

  // ---- FLA branch (MT overwrites dead Xb; AO reuses region after prefix consumes MT)
  fla_contrib32<<<dim3(64, 4, 2), blk, 0, stream>>>(Kb, Vtb, Gg, Ktg, MT, Lam);
  fla_prefix32<<<dim3(32, 8), blk, 0, stream>>>(MT, Lam, SwsT);
  fla_output_mfma<<<dim3(64, 16, 2), blk, 0, stream>>>(Qb, Gg, Ktg, SwsT, Vtb, Fla);

  // ---- base attention (AO overwrites dead MT)
  flash_attn_wave<<<dim3(512), dim3(512), 0, stream>>>(Qb, Kb, Vtb, AO);

  gemm_out2<<<dim3(16, 16), dim3(512), 0, stream>>>(AO, WoT, out, Fla);
}

// Round 14
// 353.921 us; speedup vs baseline: 1.0571x; 1.0571x over previous
//
#include <hip/hip_runtime.h>
#include <hip/hip_bf16.h>
#include <cstdint>
#include <cstddef>

// ParallelFLAAttention: B=2,N=2048,HID=2048,H=16,KVH=4,D=128,GROUPS=4
// out = softmax_causal(QK^T*s)V @ Wo + 0.01 * GLA(q,k,v)
// I/O f32; internal bf16 MFMA + f32 accum.
// R14: consolidation. Flash = R12 form (measured 69.5us): KVBLK=128 staged,
//   2x 64-key subs/round, diag peel, cvt_pk P pack, setprio, raw exp2.
//   (R13's 2-blocks/CU never engaged: 2x81920B = exactly the 160KiB pool;
//   plus longest-last dispatch of an imbalanced grid -> 92us. Reverted.)
//   Fused transposes from R13 kept (~-4us, rider-verified).
// GEMMs: QKV = m97 768-block (3/CU); final = 256x128 depth-2 pipeline.
// FLA: factorized chunk form (T=32), all MFMA; prefix depth-2 unroll.

typedef __attribute__((ext_vector_type(4))) float f32x4;
typedef __attribute__((ext_vector_type(2))) float f32x2;
typedef __attribute__((ext_vector_type(8))) short s16x8;
typedef unsigned short u16;
typedef unsigned int u32;

__device__ __forceinline__ float bfu2f(u16 u) {
  union { unsigned int i; float f; } x; x.i = ((unsigned int)u) << 16; return x.f;
}
__device__ __forceinline__ u16 f2bfu(float f) {
  union { float f; unsigned int i; } x; x.f = f;
  unsigned int r = x.i + 0x7fffu + ((x.i >> 16) & 1u);
  return (u16)(r >> 16);
}
__device__ __forceinline__ void bf8_to_f(s16x8 v, float* o) {
  union { s16x8 v; u16 u[8]; } x; x.v = v;
#pragma unroll
  for (int j = 0; j < 8; j++) o[j] = bfu2f(x.u[j]);
}
__device__ __forceinline__ s16x8 pack_bf8(f32x4 lo, f32x4 hi) {
  union { s16x8 v; u16 u[8]; } x;
#pragma unroll
  for (int j = 0; j < 4; j++) { x.u[j] = f2bfu(lo[j]); x.u[4 + j] = f2bfu(hi[j]); }
  return x.v;
}
__device__ __forceinline__ void gload_lds16(const u16* g, u16* l) {
  __builtin_amdgcn_global_load_lds(
      (__attribute__((address_space(1))) void*)(g),
      (__attribute__((address_space(3))) void*)(l), 16, 0, 0);
}

// ---------------------------------------------------------------- utility
__global__ __launch_bounds__(256) void f32_to_bf16(
    const float* __restrict__ src, u16* __restrict__ dst, int n8) {
  const int i = blockIdx.x * 256 + threadIdx.x;
  if (i < n8) {
    f32x4 a = *(const f32x4*)(src + (size_t)i * 8);
    f32x4 b = *(const f32x4*)(src + (size_t)i * 8 + 4);
    *(s16x8*)(dst + (size_t)i * 8) = pack_bf8(a, b);
  }
}

// ---------------------------------------------------------------- fused weight transposes (f32 -> bf16^T), one launch
__global__ __launch_bounds__(256) void transpose_w4(
    const float* __restrict__ Wq, const float* __restrict__ Wk,
    const float* __restrict__ Wv, const float* __restrict__ Wo,
    u16* __restrict__ WqT, u16* __restrict__ WkT,
    u16* __restrict__ WvT, u16* __restrict__ WoT) {
  __shared__ u16 tile[32][33];
  const int bid = blockIdx.x;
  const float* src; u16* dst; int R, C, bx, by;
  if (bid < 4096)      { src = Wq; dst = WqT; R = 2048; C = 2048; bx = (bid & 63) * 32; by = (bid >> 6) * 32; }
  else if (bid < 5120) { const int v = bid - 4096; src = Wk; dst = WkT; R = 2048; C = 512;  bx = (v & 15) * 32; by = (v >> 4) * 32; }
  else if (bid < 6144) { const int v = bid - 5120; src = Wv; dst = WvT; R = 2048; C = 512;  bx = (v & 15) * 32; by = (v >> 4) * 32; }
  else                 { const int v = bid - 6144; src = Wo; dst = WoT; R = 2048; C = 2048; bx = (v & 63) * 32; by = (v >> 6) * 32; }
  const int tx = threadIdx.x & 31, ty = threadIdx.x >> 5;  // 32 x 8
#pragma unroll
  for (int i = 0; i < 32; i += 8)
    tile[ty + i][tx] = f2bfu(src[(size_t)(by + ty + i) * C + bx + tx]);
  __syncthreads();
#pragma unroll
  for (int i = 0; i < 32; i += 8)
    dst[(size_t)(bx + ty + i) * R + by + tx] = tile[tx][ty + i];
}

// V transpose (bf16), both batches in one launch via blockIdx.z
__global__ __launch_bounds__(256) void transpose_bf16v(
    const u16* __restrict__ src0, u16* __restrict__ dst0) {
  __shared__ u16 tile[32][33];
  const int R = 2048, C = 512;
  const u16* src = src0 + (size_t)blockIdx.z * 2048 * 512;
  u16* dst = dst0 + (size_t)blockIdx.z * 512 * 2048;
  const int bx = blockIdx.x * 32, by = blockIdx.y * 32;
  const int tx = threadIdx.x & 31, ty = threadIdx.x >> 5;
#pragma unroll
  for (int i = 0; i < 32; i += 8)
    tile[ty + i][tx] = src[(size_t)(by + ty + i) * C + bx + tx];
  __syncthreads();
#pragma unroll
  for (int i = 0; i < 32; i += 8)
    dst[(size_t)(bx + ty + i) * R + by + tx] = tile[tx][ty + i];
}

// ---------------------------------------------------------------- merged QKV projection GEMM (m97 structure)
__global__ __launch_bounds__(256) void gemm_qkv(
    const u16* __restrict__ A, const u16* __restrict__ WqT, const u16* __restrict__ WkT,
    const u16* __restrict__ WvT, u16* __restrict__ Qo, u16* __restrict__ Ko,
    u16* __restrict__ Vo) {
  __shared__ u16 Al[128 * 32];
  __shared__ u16 Bl[128 * 32];
  const int bx = blockIdx.x;
  const u16* Bt; u16* Cb; int n0, Nst;
  if (bx < 16)      { Bt = WqT; Cb = Qo; n0 = bx * 128;        Nst = 2048; }
  else if (bx < 20) { Bt = WkT; Cb = Ko; n0 = (bx - 16) * 128; Nst = 512; }
  else              { Bt = WvT; Cb = Vo; n0 = (bx - 20) * 128; Nst = 512; }
  const int K = 2048;
  const int m0 = blockIdx.y * 128;
  const int t = threadIdx.x, w = t >> 6, l = t & 63, lm = l & 15, lq = l >> 4;
  const int wr = w >> 1, wc = w & 1;
  const f32x4 z4 = {0.f, 0.f, 0.f, 0.f};
  f32x4 acc[4][4];
#pragma unroll
  for (int i = 0; i < 4; i++)
#pragma unroll
    for (int j = 0; j < 4; j++) acc[i][j] = z4;
  const int srow = l >> 2, scol = (l & 3) * 8;
  const u16* Ag = A + (size_t)(m0 + w * 32 + srow) * K + scol;
  const u16* Bg = Bt + (size_t)(n0 + w * 32 + srow) * K + scol;
  u16* Alw = &Al[(w * 32) * 32];
  u16* Blw = &Bl[(w * 32) * 32];
  for (int kk = 0; kk < K; kk += 32) {
    gload_lds16(Ag + kk, Alw);
    gload_lds16(Ag + (size_t)16 * K + kk, Alw + 16 * 32);
    gload_lds16(Bg + kk, Blw);
    gload_lds16(Bg + (size_t)16 * K + kk, Blw + 16 * 32);
    __syncthreads();
    s16x8 af[4], bfr[4];
#pragma unroll
    for (int sm = 0; sm < 4; sm++) af[sm] = *(const s16x8*)&Al[(wr * 64 + sm * 16 + lm) * 32 + lq * 8];
#pragma unroll
    for (int sn = 0; sn < 4; sn++) bfr[sn] = *(const s16x8*)&Bl[(wc * 64 + sn * 16 + lm) * 32 + lq * 8];
#pragma unroll
    for (int sm = 0; sm < 4; sm++)
#pragma unroll
      for (int sn = 0; sn < 4; sn++)
        acc[sm][sn] = __builtin_amdgcn_mfma_f32_16x16x32_bf16(af[sm], bfr[sn], acc[sm][sn], 0, 0, 0);
    __syncthreads();
  }
#pragma unroll
  for (int sm = 0; sm < 4; sm++)
#pragma unroll
    for (int sn = 0; sn < 4; sn++)
#pragma unroll
      for (int r = 0; r < 4; r++) {
        const int row = m0 + wr * 64 + sm * 16 + lq * 4 + r;
        const int col = n0 + wc * 64 + sn * 16 + lm;
        Cb[(size_t)row * Nst + col] = f2bfu(acc[sm][sn][r]);
      }
}

// ---------------------------------------------------------------- final GEMM: 256x128 tile, depth-2 pipeline
__global__ __launch_bounds__(512) void gemm_out2(
    const u16* __restrict__ A, const u16* __restrict__ Bt, float* __restrict__ Cf,
    const u16* __restrict__ addsrc) {
  __shared__ u16 Abuf[3 * 16384];
  __shared__ u16 Bbuf[3 * 8192];
  int f = blockIdx.y * 16 + blockIdx.x;   // 0..255
  f = (f & 7) * 32 + (f >> 3);            // bijective XCD swizzle (256%8==0)
  const int by = f >> 4, bx = f & 15;
  const int m0 = by * 256, n0 = bx * 128;
  const int K = 2048, Nst = 2048;
  const int t = threadIdx.x, w = t >> 6, l = t & 63, lm = l & 15, lq = l >> 4;
  const int wr = w >> 1, wc = w & 1;
  const int tr = t >> 3, tc8 = (t & 7) * 8;   // staging row-in-64 / col-u16 base
  const f32x4 z4 = {0.f, 0.f, 0.f, 0.f};
  f32x4 acc[4][4];
#pragma unroll
  for (int i = 0; i < 4; i++)
#pragma unroll
    for (int j = 0; j < 4; j++) acc[i][j] = z4;
  const u16* Ag = A + (size_t)m0 * K;
  const u16* Bg = Bt + (size_t)n0 * K;
  auto stage = [&](int kt, int bufi) {
#pragma unroll
    for (int i = 0; i < 4; i++) {
      const int row = i * 64 + tr;
      const int col = tc8 ^ ((row & 7) << 3);  // pre-swizzled source (u16)
      gload_lds16(Ag + (size_t)row * K + kt * 64 + col,
                  Abuf + bufi * 16384 + i * 4096 + w * 512);
    }
#pragma unroll
    for (int i = 0; i < 2; i++) {
      const int row = i * 64 + tr;
      const int col = tc8 ^ ((row & 7) << 3);
      gload_lds16(Bg + (size_t)row * K + kt * 64 + col,
                  Bbuf + bufi * 8192 + i * 4096 + w * 512);
    }
  };
  const int nt = K >> 6;  // 32
  stage(0, 0);
  stage(1, 1);
  int cur = 0;
#pragma unroll 1
  for (int kt = 0; kt < nt; kt++) {
    if (kt + 2 < nt) {
      int nb = cur + 2; if (nb >= 3) nb -= 3;
      stage(kt + 2, nb);
      asm volatile("s_waitcnt vmcnt(12)" ::: "memory");  // kt done; kt+1,kt+2 in flight
    } else if (kt + 1 < nt) {
      asm volatile("s_waitcnt vmcnt(6)" ::: "memory");   // kt done; kt+1 in flight
    } else {
      asm volatile("s_waitcnt vmcnt(0)" ::: "memory");
    }
    __builtin_amdgcn_s_barrier();
    const u16* Ab = Abuf + cur * 16384;
    const u16* Bb = Bbuf + cur * 8192;
    s16x8 af[4][2], bff[4][2];
#pragma unroll
    for (int sm = 0; sm < 4; sm++) {
      const int row = wr * 64 + sm * 16 + lm;
#pragma unroll
      for (int kk = 0; kk < 2; kk++)
        af[sm][kk] = *(const s16x8*)&Ab[row * 64 +
            ((((kk << 6) | (lq << 4)) ^ ((row & 7) << 4)) >> 1)];
    }
#pragma unroll
    for (int sn = 0; sn < 4; sn++) {
      const int row = wc * 64 + sn * 16 + lm;
#pragma unroll
      for (int kk = 0; kk < 2; kk++)
        bff[sn][kk] = *(const s16x8*)&Bb[row * 64 +
            ((((kk << 6) | (lq << 4)) ^ ((row & 7) << 4)) >> 1)];
    }
#pragma unroll
    for (int kk = 0; kk < 2; kk++)
#pragma unroll
      for (int sm = 0; sm < 4; sm++)
#pragma unroll
        for (int sn = 0; sn < 4; sn++)
          acc[sm][sn] = __builtin_amdgcn_mfma_f32_16x16x32_bf16(
              af[sm][kk], bff[sn][kk], acc[sm][sn], 0, 0, 0);
    asm volatile("s_waitcnt lgkmcnt(0)" ::: "memory");
    __builtin_amdgcn_s_barrier();
    cur = (cur == 2) ? 0 : cur + 1;
  }
#pragma unroll
  for (int sm = 0; sm < 4; sm++)
#pragma unroll
    for (int sn = 0; sn < 4; sn++)
#pragma unroll
      for (int r = 0; r < 4; r++) {
        const int row = m0 + wr * 64 + sm * 16 + lq * 4 + r;
        const int col = n0 + wc * 64 + sn * 16 + lm;
        float v = acc[sm][sn][r] + 0.01f * bfu2f(addsrc[(size_t)row * Nst + col]);
        Cf[(size_t)row * Nst + col] = v;
      }
}

// ---------------------------------------------------------------- flash attention: KVBLK=128 staged, 2x 64-key subs (R12 form)
// 256 blocks x 512 threads. bid -> set=bid&7 (b*4+kvh), rest=bid>>3:
// j0=rest>>1 (0..15), hp=rest&1. Phase ph: j = ph ? 31-j0 : j0.
// Wave w: head h = kvh*4 + hp*2 + (w&1); chunk c = 2j + ((w>>1)&1);
// row-half mh = w>>2. Balanced by construction (33 kt-units/block).
__global__ __launch_bounds__(512) void flash_attn_wave(
    const u16* __restrict__ Q, const u16* __restrict__ Kx,
    const u16* __restrict__ Vt, u16* __restrict__ AO) {
  __shared__ u16 Klds[2][128 * 128];  // [buf][key][d], 2x32 KB, swizzled contents
  __shared__ u16 Vlds[2][128 * 128];  // [buf][d][key], 2x32 KB, swizzled contents
  __shared__ u16 Pl[8][16][68];       // per-wave P tile, 17408 B
  const int bid = blockIdx.x;
  const int set = bid & 7;
  const int b = set >> 2, kvh = set & 3;
  const int rest = bid >> 3;
  const int j0 = rest >> 1, hp = rest & 1;
  const int t = threadIdx.x, w = t >> 6, l = t & 63, lm = l & 15, lq = l >> 4;
  const int h = kvh * 4 + hp * 2 + (w & 1);
  const int cs = (w >> 1) & 1, mh = w >> 2;
  const float scale2 = 0.127517827f;   // (1/sqrt(128)) * log2(e)
  const u16* Kbase = Kx + (size_t)(b * 2048) * 512 + kvh * 128;
  const u16* Vbase = Vt + (size_t)(b * 512 + kvh * 128) * 2048;
  const f32x4 z4 = {0.f, 0.f, 0.f, 0.f};

  auto stage = [&](int s, int bufi) {
    const int key0 = s * 128;
#pragma unroll
    for (int r = 0; r < 4; r++) {
      const int row = r * 32 + w * 4 + (l >> 4);
      const int scb = ((l & 15) * 16) ^ ((row & 7) << 4);
      gload_lds16(Kbase + (size_t)(key0 + row) * 512 + (scb >> 1),
                  &Klds[bufi][r * 4096 + w * 512]);
    }
#pragma unroll
    for (int r = 0; r < 4; r++) {
      const int row = r * 32 + w * 4 + (l >> 4);
      const int scb = ((l & 15) * 16) ^ ((row & 7) << 4);
      gload_lds16(Vbase + (size_t)row * 2048 + key0 + (scb >> 1),
                  &Vlds[bufi][r * 4096 + w * 512]);
    }
  };

#pragma unroll 1
  for (int ph = 0; ph < 2; ph++) {
    const int j = ph ? (31 - j0) : j0;
    const int c = 2 * j + cs;
    const int base = c * 32;
    const int nst128 = (j + 2) >> 1;   // 128-key stages
    int cur = 0;
    stage(0, 0);
    // Q fragment for this wave's 16 rows
    s16x8 qf[4];
#pragma unroll
    for (int kk = 0; kk < 4; kk++)
      qf[kk] = *(const s16x8*)(Q + ((size_t)(b * 2048 + base + mh * 16 + lm)) * 2048 +
                               h * 128 + kk * 32 + lq * 8);
    f32x4 oacc[8];
#pragma unroll
    for (int e = 0; e < 8; e++) oacc[e] = z4;
    float lsum[4] = {0.f, 0.f, 0.f, 0.f};

    // one 64-key compute sub-iteration from staged buffers
    auto compute64 = [&](int tile, const char* KB, const char* VB, int sub) {
      const int key0 = tile * 64;
      s16x8 kf[4][4];
#pragma unroll
      for (int nst = 0; nst < 4; nst++)
#pragma unroll
        for (int kk = 0; kk < 4; kk++) {
          const int row = sub * 64 + nst * 16 + lm;
          const int cb = (kk * 64 + lq * 16) ^ ((row & 7) << 4);
          kf[nst][kk] = *(const s16x8*)(KB + row * 256 + cb);
        }
      f32x4 sacc[4];
#pragma unroll
      for (int i = 0; i < 4; i++) sacc[i] = z4;
      __builtin_amdgcn_s_setprio(1);
#pragma unroll
      for (int nst = 0; nst < 4; nst++)
#pragma unroll
        for (int kk = 0; kk < 4; kk++)
          sacc[nst] = __builtin_amdgcn_mfma_f32_16x16x32_bf16(
              qf[kk], kf[nst][kk], sacc[nst], 0, 0, 0);
      __builtin_amdgcn_s_setprio(0);
      // exp (all tiles); mask only on the diagonal tile (uniform branch)
      float pv[4][4];
#pragma unroll
      for (int r = 0; r < 4; r++)
#pragma unroll
        for (int nst = 0; nst < 4; nst++)
          pv[r][nst] = __builtin_amdgcn_exp2f(sacc[nst][r] * scale2);
      if (tile == j) {
#pragma unroll
        for (int r = 0; r < 4; r++) {
          const int qrow = base + mh * 16 + lq * 4 + r;
#pragma unroll
          for (int nst = 0; nst < 4; nst++)
            if (key0 + nst * 16 + lm > qrow) pv[r][nst] = 0.f;
        }
      }
#pragma unroll
      for (int r = 0; r < 4; r++) {
        lsum[r] += (pv[r][0] + pv[r][1]) + (pv[r][2] + pv[r][3]);
        u32 p01, p23;
        asm("v_cvt_pk_bf16_f32 %0, %1, %2" : "=v"(p01) : "v"(pv[r][0]), "v"(pv[r][1]));
        asm("v_cvt_pk_bf16_f32 %0, %1, %2" : "=v"(p23) : "v"(pv[r][2]), "v"(pv[r][3]));
        u16* prow = &Pl[w][lq * 4 + r][lm];
        prow[0]  = (u16)p01;
        prow[16] = (u16)(p01 >> 16);
        prow[32] = (u16)p23;
        prow[48] = (u16)(p23 >> 16);
      }
      // ---- PV
      s16x8 vf[8][2];
#pragma unroll
      for (int et = 0; et < 8; et++)
#pragma unroll
        for (int kc = 0; kc < 2; kc++) {
          const int row = et * 16 + lm;
          const int cb = (sub * 128 + kc * 64 + lq * 16) ^ ((row & 7) << 4);
          vf[et][kc] = *(const s16x8*)(VB + row * 256 + cb);
        }
      s16x8 pf[2];
#pragma unroll
      for (int kc = 0; kc < 2; kc++)
        pf[kc] = *(const s16x8*)&Pl[w][lm][kc * 32 + lq * 8];
      __builtin_amdgcn_s_setprio(1);
#pragma unroll
      for (int et = 0; et < 8; et++)
#pragma unroll
        for (int kc = 0; kc < 2; kc++)
          oacc[et] = __builtin_amdgcn_mfma_f32_16x16x32_bf16(
              pf[kc], vf[et][kc], oacc[et], 0, 0, 0);
      __builtin_amdgcn_s_setprio(0);
    };

#pragma unroll 1
    for (int s = 0; s < nst128; s++) {
      if (s + 1 < nst128) {
        stage(s + 1, cur ^ 1);
        asm volatile("s_waitcnt vmcnt(8)" ::: "memory");
      } else {
        asm volatile("s_waitcnt vmcnt(0)" ::: "memory");
      }
      __builtin_amdgcn_s_barrier();
      const char* KB = (const char*)&Klds[cur][0];
      const char* VB = (const char*)&Vlds[cur][0];
      compute64(2 * s, KB, VB, 0);
      if (2 * s + 1 <= j) compute64(2 * s + 1, KB, VB, 1);
      asm volatile("s_waitcnt lgkmcnt(0)" ::: "memory");
      __builtin_amdgcn_s_barrier();
      cur ^= 1;
    }
    // ---- normalize + store
#pragma unroll
    for (int r = 0; r < 4; r++) {
#pragma unroll
      for (int off = 1; off < 16; off <<= 1)
        lsum[r] += __shfl_xor(lsum[r], off, 64);
    }
#pragma unroll
    for (int r = 0; r < 4; r++) {
      const float inv = 1.f / lsum[r];
      const int row = base + mh * 16 + lq * 4 + r;
      u16* op = AO + ((size_t)(b * 2048 + row)) * 2048 + h * 128;
#pragma unroll
      for (int et = 0; et < 8; et++) op[et * 16 + lm] = f2bfu(oacc[et][r] * inv);
    }
  }
}

// ---------------------------------------------------------------- FLA: per-32-chunk gates + contribution
__global__ __launch_bounds__(256) void fla_contrib32(
    const u16* __restrict__ Kx, const u16* __restrict__ Vt,
    u16* __restrict__ Gg, u16* __restrict__ Ktg, u16* __restrict__ MT,
    float* __restrict__ Lam) {
  __shared__ float gl[32][132];
  __shared__ float kl[32][132];
  __shared__ float ktl[32][132];
  __shared__ u16 khT[128][40];
  const int c = blockIdx.x, kvh = blockIdx.y, b = blockIdx.z;
  const int bk = b * 4 + kvh;
  const int t = threadIdx.x;
  const size_t cb = (size_t)bk * 64 + c;
  {
    const int r = t >> 3, c0 = (t & 7) * 16;
    const u16* kp = Kx + ((size_t)(b * 2048 + c * 32 + r)) * 512 + kvh * 128 + c0;
#pragma unroll
    for (int i = 0; i < 2; i++) {
      float kv[8];
      bf8_to_f(*(const s16x8*)(kp + i * 8), kv);
#pragma unroll
      for (int j = 0; j < 8; j++) {
        kl[r][c0 + i * 8 + j] = kv[j];
        gl[r][c0 + i * 8 + j] = 1.f / (1.f + __expf(-kv[j]));
      }
    }
  }
  __syncthreads();
  if (t < 128) {  // one thread per d: cumprod + ktilde + khat^T
    float G = 1.f;
#pragma unroll
    for (int s = 0; s < 32; s++) {
      G *= gl[s][t];
      gl[s][t] = G;
      ktl[s][t] = kl[s][t] / G;
    }
    Lam[cb * 128 + t] = G;
    const float lam = G;
#pragma unroll
    for (int s = 0; s < 32; s++) khT[t][s] = f2bfu(ktl[s][t] * lam);
  }
  __syncthreads();
  {
    const int r = t >> 3, c0 = (t & 7) * 16;
    u16* gp = Gg + cb * 4096 + r * 128 + c0;
    u16* kp = Ktg + cb * 4096 + r * 128 + c0;
#pragma unroll
    for (int i = 0; i < 2; i++) {
      f32x4 a = *(f32x4*)&gl[r][c0 + i * 8];
      f32x4 b2 = *(f32x4*)&gl[r][c0 + i * 8 + 4];
      *(s16x8*)(gp + i * 8) = pack_bf8(a, b2);
      a = *(f32x4*)&ktl[r][c0 + i * 8];
      b2 = *(f32x4*)&ktl[r][c0 + i * 8 + 4];
      *(s16x8*)(kp + i * 8) = pack_bf8(a, b2);
    }
  }
  const int w = t >> 6, l = t & 63, lm = l & 15, lq = l >> 4;
  const f32x4 z4 = {0.f, 0.f, 0.f, 0.f};
  f32x4 macc[2][8];
#pragma unroll
  for (int ei = 0; ei < 2; ei++)
#pragma unroll
    for (int dt = 0; dt < 8; dt++) macc[ei][dt] = z4;
  s16x8 vtf[2];
#pragma unroll
  for (int ei = 0; ei < 2; ei++) {
    const int et = w * 2 + ei;
    vtf[ei] = *(const s16x8*)(Vt + ((size_t)(b * 512 + kvh * 128 + et * 16 + lm)) * 2048 +
                              c * 32 + lq * 8);
  }
#pragma unroll
  for (int dt = 0; dt < 8; dt++) {
    s16x8 kf = *(const s16x8*)&khT[dt * 16 + lm][lq * 8];
#pragma unroll
    for (int ei = 0; ei < 2; ei++)
      macc[ei][dt] = __builtin_amdgcn_mfma_f32_16x16x32_bf16(vtf[ei], kf, macc[ei][dt], 0, 0, 0);
  }
  u16* mp = MT + cb * 16384;
#pragma unroll
  for (int ei = 0; ei < 2; ei++)
#pragma unroll
    for (int dt = 0; dt < 8; dt++)
#pragma unroll
      for (int r = 0; r < 4; r++)
        mp[(size_t)((w * 2 + ei) * 16 + lq * 4 + r) * 128 + dt * 16 + lm] =
            f2bfu(macc[ei][dt][r]);
}

// ---------------------------------------------------------------- FLA prefix: parallel over (bk,e,d), depth-2 prefetch
__global__ __launch_bounds__(256) void fla_prefix32(
    const u16* __restrict__ MT, const float* __restrict__ Lam, u16* __restrict__ SwsT) {
  const int eg = blockIdx.x, bk = blockIdx.y;
  const int t = threadIdx.x;
  const int e = eg * 4 + (t >> 6), d0 = (t & 63) * 2;
  const size_t cb0 = (size_t)bk * 64;
  const u16* mp = MT + cb0 * 16384 + e * 128 + d0;
  const float* lp = Lam + cb0 * 128 + d0;
  u16* sp = SwsT + cb0 * 16384 + e * 128 + d0;
  float s0 = 0.f, s1 = 0.f;
  u32 ma = *(const u32*)mp;
  u32 mb = *(const u32*)(mp + 16384);
  f32x2 la = *(const f32x2*)lp;
  f32x2 lb = *(const f32x2*)(lp + 128);
#pragma unroll 1
  for (int c = 0; c < 64; c += 2) {
    u32 na = 0, nb = 0;
    f32x2 nla = {0.f, 0.f}, nlb = {0.f, 0.f};
    if (c + 2 < 64) {
      na = *(const u32*)(mp + (size_t)(c + 2) * 16384);
      nla = *(const f32x2*)(lp + (size_t)(c + 2) * 128);
      nb = *(const u32*)(mp + (size_t)(c + 3) * 16384);
      nlb = *(const f32x2*)(lp + (size_t)(c + 3) * 128);
    }
    *(u32*)(sp + (size_t)c * 16384) = (u32)f2bfu(s0) | ((u32)f2bfu(s1) << 16);
    s0 = s0 * la[0] + bfu2f((u16)(ma & 0xffffu));
    s1 = s1 * la[1] + bfu2f((u16)(ma >> 16));
    *(u32*)(sp + (size_t)(c + 1) * 16384) = (u32)f2bfu(s0) | ((u32)f2bfu(s1) << 16);
    s0 = s0 * lb[0] + bfu2f((u16)(mb & 0xffffu));
    s1 = s1 * lb[1] + bfu2f((u16)(mb >> 16));
    ma = na; mb = nb; la = nla; lb = nlb;
  }
}

// ---------------------------------------------------------------- FLA output: O = scale*(q~ S0 + tril(q~ k~^T) v)
__global__ __launch_bounds__(256) void fla_output_mfma(
    const u16* __restrict__ Q, const u16* __restrict__ Gg, const u16* __restrict__ Ktg,
    const u16* __restrict__ SwsT, const u16* __restrict__ Vt, u16* __restrict__ Fla) {
  __shared__ u16 Pl[4][2][16][40];
  const int c = blockIdx.x, h = blockIdx.y, b = blockIdx.z;
  const int kvh = h >> 2, bk = b * 4 + kvh;
  const int t = threadIdx.x, w = t >> 6, l = t & 63, lm = l & 15, lq = l >> 4;
  const float scale = 0.0883883476483184f;
  const size_t cb = (size_t)bk * 64 + c;
  const f32x4 z4 = {0.f, 0.f, 0.f, 0.f};
  s16x8 qgf[2][4];
#pragma unroll
  for (int m = 0; m < 2; m++)
#pragma unroll
    for (int kk = 0; kk < 4; kk++) {
      float qv[8], gv[8];
      bf8_to_f(*(const s16x8*)(Q + ((size_t)(b * 2048 + c * 32 + m * 16 + lm)) * 2048 +
                               h * 128 + kk * 32 + lq * 8), qv);
      bf8_to_f(*(const s16x8*)(Gg + cb * 4096 + (m * 16 + lm) * 128 + kk * 32 + lq * 8), gv);
      f32x4 a, b2;
#pragma unroll
      for (int j = 0; j < 4; j++) { a[j] = qv[j] * gv[j]; b2[j] = qv[4 + j] * gv[4 + j]; }
      qgf[m][kk] = pack_bf8(a, b2);
    }
  f32x4 sacc[2][2];
#pragma unroll
  for (int m = 0; m < 2; m++)
#pragma unroll
    for (int st = 0; st < 2; st++) sacc[m][st] = z4;
#pragma unroll
  for (int st = 0; st < 2; st++)
#pragma unroll
    for (int kk = 0; kk < 4; kk++) {
      s16x8 ktf = *(const s16x8*)(Ktg + cb * 4096 + (st * 16 + lm) * 128 + kk * 32 + lq * 8);
#pragma unroll
      for (int m = 0; m < 2; m++)
        sacc[m][st] = __builtin_amdgcn_mfma_f32_16x16x32_bf16(qgf[m][kk], ktf, sacc[m][st], 0, 0, 0);
    }
#pragma unroll
  for (int m = 0; m < 2; m++)
#pragma unroll
    for (int st = 0; st < 2; st++)
#pragma unroll
      for (int r = 0; r < 4; r++) {
        const int trow = m * 16 + lq * 4 + r;
        const int scol = st * 16 + lm;
        Pl[w][m][lq * 4 + r][st * 16 + lm] = f2bfu(scol <= trow ? sacc[m][st][r] : 0.f);
      }
  s16x8 pf[2];
#pragma unroll
  for (int m = 0; m < 2; m++) pf[m] = *(const s16x8*)&Pl[w][m][lm][lq * 8];
  f32x4 oacc[2][2];
#pragma unroll
  for (int m = 0; m < 2; m++)
#pragma unroll
    for (int ei = 0; ei < 2; ei++) oacc[m][ei] = z4;
#pragma unroll
  for (int ei = 0; ei < 2; ei++) {
    const int et = w * 2 + ei;
    s16x8 vtf = *(const s16x8*)(Vt + ((size_t)(b * 512 + kvh * 128 + et * 16 + lm)) * 2048 +
                                c * 32 + lq * 8);
#pragma unroll
    for (int m = 0; m < 2; m++)
      oacc[m][ei] = __builtin_amdgcn_mfma_f32_16x16x32_bf16(pf[m], vtf, oacc[m][ei], 0, 0, 0);
#pragma unroll
    for (int kk = 0; kk < 4; kk++) {
      s16x8 s0f = *(const s16x8*)(SwsT + cb * 16384 + (et * 16 + lm) * 128 + kk * 32 + lq * 8);
#pragma unroll
      for (int m = 0; m < 2; m++)
        oacc[m][ei] = __builtin_amdgcn_mfma_f32_16x16x32_bf16(qgf[m][kk], s0f, oacc[m][ei], 0, 0, 0);
    }
  }
#pragma unroll
  for (int m = 0; m < 2; m++)
#pragma unroll
    for (int ei = 0; ei < 2; ei++)
#pragma unroll
      for (int r = 0; r < 4; r++)
        Fla[((size_t)(b * 2048 + c * 32 + m * 16 + lq * 4 + r)) * 2048 + h * 128 +
            (w * 2 + ei) * 16 + lm] = f2bfu(scale * oacc[m][ei][r]);
}

// ---------------------------------------------------------------- launch
extern "C" void kernel_launch(void* const* d_in, const int* in_sizes, int n_in,
                              void* d_out, int out_size, void* d_ws, size_t ws_size,
                              hipStream_t stream) {
  const float* X  = (const float*)d_in[0];
  const float* Wq = (const float*)d_in[1];
  const float* Wk = (const float*)d_in[2];
  const float* Wv = (const float*)d_in[3];
  const float* Wo = (const float*)d_in[4];
  float* out = (float*)d_out;

  char* ws = (char*)d_ws;
  size_t off = 0;
  auto alloc = [&](size_t bytes) { void* p = ws + off; off += (bytes + 255) & ~(size_t)255; return p; };
  u16* WoT = (u16*)alloc(2048ull * 2048 * 2);     // 8 MB, live to end
  u16* Qb  = (u16*)alloc(4096ull * 2048 * 2);     // 16 MB
  u16* Kb  = (u16*)alloc(4096ull * 512 * 2);      // 4 MB
  u16* Vb  = (u16*)alloc(4096ull * 512 * 2);      // 4 MB
  u16* Vtb = (u16*)alloc(2ull * 512 * 2048 * 2);  // 4 MB
  u16* Fla = (u16*)alloc(4096ull * 2048 * 2);     // 16 MB
  // time-shared 16 MB region: Xb (until KV proj) -> MT (contrib..prefix) -> AO (flash..end)
  u16* SH16 = (u16*)alloc(4096ull * 2048 * 2);
  u16* Xb = SH16;
  u16* MT = SH16;
  u16* AO = SH16;
  // time-shared scratch: WqT/WkT/WvT early; G/ktilde/SwsT/Lam after projections
  char* BIG = (char*)alloc(26ull * 1024 * 1024);
  u16* WqT = (u16*)BIG;                            // 8 MB
  u16* WkT = (u16*)(BIG + 8ull * 1024 * 1024);     // 2 MB
  u16* WvT = (u16*)(BIG + 10ull * 1024 * 1024);    // 2 MB
  u16* Gg   = (u16*)BIG;                           // 4 MB
  u16* Ktg  = (u16*)(BIG + 4194304ull);            // 4 MB
  u16* SwsT = (u16*)(BIG + 8388608ull);            // 16.78 MB
  float* Lam = (float*)(BIG + 8388608ull + 16777216ull);  // 256 KB
  (void)ws_size; (void)in_sizes; (void)n_in; (void)out_size;

  dim3 blk(256);
  f32_to_bf16<<<dim3(4096), blk, 0, stream>>>(X, Xb, 4096 * 2048 / 8);
  transpose_w4<<<dim3(10240), blk, 0, stream>>>(Wq, Wk, Wv, Wo, WqT, WkT, WvT, WoT);

  gemm_qkv<<<dim3(24, 32), blk, 0, stream>>>(Xb, WqT, WkT, WvT, Qb, Kb, Vb);

  transpose_bf16v<<<dim3(16, 64, 2), blk, 0, stream>>>(Vb, Vtb);

  // ---- FLA branch (MT overwrites dead Xb; AO reuses region after prefix consumes MT)
  fla_contrib32<<<dim3(64, 4, 2), blk, 0, stream>>>(Kb, Vtb, Gg, Ktg, MT, Lam);
  fla_prefix32<<<dim3(32, 8), blk, 0, stream>>>(MT, Lam, SwsT);
  fla_output_mfma<<<dim3(64, 16, 2), blk, 0, stream>>>(Qb, Gg, Ktg, SwsT, Vtb, Fla);

  // ---- base attention (AO overwrites dead MT)
  flash_attn_wave<<<dim3(256), dim3(512), 0, stream>>>(Qb, Kb, Vtb, AO);

  gemm_out2<<<dim3(16, 16), dim3(512), 0, stream>>>(AO, WoT, out, Fla);
}

// Round 15
// 347.831 us; speedup vs baseline: 1.0756x; 1.0175x over previous
//
#include <hip/hip_runtime.h>
#include <hip/hip_bf16.h>
#include <cstdint>
#include <cstddef>

// ParallelFLAAttention: B=2,N=2048,HID=2048,H=16,KVH=4,D=128,GROUPS=4
// out = softmax_causal(QK^T*s)V @ Wo + 0.01 * GLA(q,k,v)
// I/O f32; internal bf16 MFMA + f32 accum.
// R15 flash: TRUE 2 blocks/CU. 64 KB LDS (K dbuf 32K + V single 16K +
//   packed Pl 16K; R13's 81920B x2 = exactly the pool and didn't double-
//   fit). 512 blocks, one phase each, complementary-j mapping (bid<256 ->
//   j0, bid>=256 -> 31-j0) so round-robin CU pairs sum to 33 units; all
//   blocks co-resident from t=0 -> no dispatch tail. Single-V sequencing:
//   issue V(kt)+K(kt+1); vmcnt(4); bar; QK/exp/P; vmcnt(2); bar; PV; bar.
//   R12 VALU trims kept (diag peel, cvt_pk pack, setprio, raw exp2).
// GEMMs: QKV = m97 768-block (3/CU); final = 256x128 depth-2 pipeline.
// FLA: factorized chunk form (T=32), all MFMA; prefix depth-2 unroll.

typedef __attribute__((ext_vector_type(4))) float f32x4;
typedef __attribute__((ext_vector_type(2))) float f32x2;
typedef __attribute__((ext_vector_type(8))) short s16x8;
typedef unsigned short u16;
typedef unsigned int u32;

__device__ __forceinline__ float bfu2f(u16 u) {
  union { unsigned int i; float f; } x; x.i = ((unsigned int)u) << 16; return x.f;
}
__device__ __forceinline__ u16 f2bfu(float f) {
  union { float f; unsigned int i; } x; x.f = f;
  unsigned int r = x.i + 0x7fffu + ((x.i >> 16) & 1u);
  return (u16)(r >> 16);
}
__device__ __forceinline__ void bf8_to_f(s16x8 v, float* o) {
  union { s16x8 v; u16 u[8]; } x; x.v = v;
#pragma unroll
  for (int j = 0; j < 8; j++) o[j] = bfu2f(x.u[j]);
}
__device__ __forceinline__ s16x8 pack_bf8(f32x4 lo, f32x4 hi) {
  union { s16x8 v; u16 u[8]; } x;
#pragma unroll
  for (int j = 0; j < 4; j++) { x.u[j] = f2bfu(lo[j]); x.u[4 + j] = f2bfu(hi[j]); }
  return x.v;
}
__device__ __forceinline__ void gload_lds16(const u16* g, u16* l) {
  __builtin_amdgcn_global_load_lds(
      (__attribute__((address_space(1))) void*)(g),
      (__attribute__((address_space(3))) void*)(l), 16, 0, 0);
}

// ---------------------------------------------------------------- utility
__global__ __launch_bounds__(256) void f32_to_bf16(
    const float* __restrict__ src, u16* __restrict__ dst, int n8) {
  const int i = blockIdx.x * 256 + threadIdx.x;
  if (i < n8) {
    f32x4 a = *(const f32x4*)(src + (size_t)i * 8);
    f32x4 b = *(const f32x4*)(src + (size_t)i * 8 + 4);
    *(s16x8*)(dst + (size_t)i * 8) = pack_bf8(a, b);
  }
}

// ---------------------------------------------------------------- fused weight transposes (f32 -> bf16^T), one launch
__global__ __launch_bounds__(256) void transpose_w4(
    const float* __restrict__ Wq, const float* __restrict__ Wk,
    const float* __restrict__ Wv, const float* __restrict__ Wo,
    u16* __restrict__ WqT, u16* __restrict__ WkT,
    u16* __restrict__ WvT, u16* __restrict__ WoT) {
  __shared__ u16 tile[32][33];
  const int bid = blockIdx.x;
  const float* src; u16* dst; int R, C, bx, by;
  if (bid < 4096)      { src = Wq; dst = WqT; R = 2048; C = 2048; bx = (bid & 63) * 32; by = (bid >> 6) * 32; }
  else if (bid < 5120) { const int v = bid - 4096; src = Wk; dst = WkT; R = 2048; C = 512;  bx = (v & 15) * 32; by = (v >> 4) * 32; }
  else if (bid < 6144) { const int v = bid - 5120; src = Wv; dst = WvT; R = 2048; C = 512;  bx = (v & 15) * 32; by = (v >> 4) * 32; }
  else                 { const int v = bid - 6144; src = Wo; dst = WoT; R = 2048; C = 2048; bx = (v & 63) * 32; by = (v >> 6) * 32; }
  const int tx = threadIdx.x & 31, ty = threadIdx.x >> 5;  // 32 x 8
#pragma unroll
  for (int i = 0; i < 32; i += 8)
    tile[ty + i][tx] = f2bfu(src[(size_t)(by + ty + i) * C + bx + tx]);
  __syncthreads();
#pragma unroll
  for (int i = 0; i < 32; i += 8)
    dst[(size_t)(bx + ty + i) * R + by + tx] = tile[tx][ty + i];
}

// V transpose (bf16), both batches in one launch via blockIdx.z
__global__ __launch_bounds__(256) void transpose_bf16v(
    const u16* __restrict__ src0, u16* __restrict__ dst0) {
  __shared__ u16 tile[32][33];
  const int R = 2048, C = 512;
  const u16* src = src0 + (size_t)blockIdx.z * 2048 * 512;
  u16* dst = dst0 + (size_t)blockIdx.z * 512 * 2048;
  const int bx = blockIdx.x * 32, by = blockIdx.y * 32;
  const int tx = threadIdx.x & 31, ty = threadIdx.x >> 5;
#pragma unroll
  for (int i = 0; i < 32; i += 8)
    tile[ty + i][tx] = src[(size_t)(by + ty + i) * C + bx + tx];
  __syncthreads();
#pragma unroll
  for (int i = 0; i < 32; i += 8)
    dst[(size_t)(bx + ty + i) * R + by + tx] = tile[tx][ty + i];
}

// ---------------------------------------------------------------- merged QKV projection GEMM (m97 structure)
__global__ __launch_bounds__(256) void gemm_qkv(
    const u16* __restrict__ A, const u16* __restrict__ WqT, const u16* __restrict__ WkT,
    const u16* __restrict__ WvT, u16* __restrict__ Qo, u16* __restrict__ Ko,
    u16* __restrict__ Vo) {
  __shared__ u16 Al[128 * 32];
  __shared__ u16 Bl[128 * 32];
  const int bx = blockIdx.x;
  const u16* Bt; u16* Cb; int n0, Nst;
  if (bx < 16)      { Bt = WqT; Cb = Qo; n0 = bx * 128;        Nst = 2048; }
  else if (bx < 20) { Bt = WkT; Cb = Ko; n0 = (bx - 16) * 128; Nst = 512; }
  else              { Bt = WvT; Cb = Vo; n0 = (bx - 20) * 128; Nst = 512; }
  const int K = 2048;
  const int m0 = blockIdx.y * 128;
  const int t = threadIdx.x, w = t >> 6, l = t & 63, lm = l & 15, lq = l >> 4;
  const int wr = w >> 1, wc = w & 1;
  const f32x4 z4 = {0.f, 0.f, 0.f, 0.f};
  f32x4 acc[4][4];
#pragma unroll
  for (int i = 0; i < 4; i++)
#pragma unroll
    for (int j = 0; j < 4; j++) acc[i][j] = z4;
  const int srow = l >> 2, scol = (l & 3) * 8;
  const u16* Ag = A + (size_t)(m0 + w * 32 + srow) * K + scol;
  const u16* Bg = Bt + (size_t)(n0 + w * 32 + srow) * K + scol;
  u16* Alw = &Al[(w * 32) * 32];
  u16* Blw = &Bl[(w * 32) * 32];
  for (int kk = 0; kk < K; kk += 32) {
    gload_lds16(Ag + kk, Alw);
    gload_lds16(Ag + (size_t)16 * K + kk, Alw + 16 * 32);
    gload_lds16(Bg + kk, Blw);
    gload_lds16(Bg + (size_t)16 * K + kk, Blw + 16 * 32);
    __syncthreads();
    s16x8 af[4], bfr[4];
#pragma unroll
    for (int sm = 0; sm < 4; sm++) af[sm] = *(const s16x8*)&Al[(wr * 64 + sm * 16 + lm) * 32 + lq * 8];
#pragma unroll
    for (int sn = 0; sn < 4; sn++) bfr[sn] = *(const s16x8*)&Bl[(wc * 64 + sn * 16 + lm) * 32 + lq * 8];
#pragma unroll
    for (int sm = 0; sm < 4; sm++)
#pragma unroll
      for (int sn = 0; sn < 4; sn++)
        acc[sm][sn] = __builtin_amdgcn_mfma_f32_16x16x32_bf16(af[sm], bfr[sn], acc[sm][sn], 0, 0, 0);
    __syncthreads();
  }
#pragma unroll
  for (int sm = 0; sm < 4; sm++)
#pragma unroll
    for (int sn = 0; sn < 4; sn++)
#pragma unroll
      for (int r = 0; r < 4; r++) {
        const int row = m0 + wr * 64 + sm * 16 + lq * 4 + r;
        const int col = n0 + wc * 64 + sn * 16 + lm;
        Cb[(size_t)row * Nst + col] = f2bfu(acc[sm][sn][r]);
      }
}

// ---------------------------------------------------------------- final GEMM: 256x128 tile, depth-2 pipeline
__global__ __launch_bounds__(512) void gemm_out2(
    const u16* __restrict__ A, const u16* __restrict__ Bt, float* __restrict__ Cf,
    const u16* __restrict__ addsrc) {
  __shared__ u16 Abuf[3 * 16384];
  __shared__ u16 Bbuf[3 * 8192];
  int f = blockIdx.y * 16 + blockIdx.x;   // 0..255
  f = (f & 7) * 32 + (f >> 3);            // bijective XCD swizzle (256%8==0)
  const int by = f >> 4, bx = f & 15;
  const int m0 = by * 256, n0 = bx * 128;
  const int K = 2048, Nst = 2048;
  const int t = threadIdx.x, w = t >> 6, l = t & 63, lm = l & 15, lq = l >> 4;
  const int wr = w >> 1, wc = w & 1;
  const int tr = t >> 3, tc8 = (t & 7) * 8;   // staging row-in-64 / col-u16 base
  const f32x4 z4 = {0.f, 0.f, 0.f, 0.f};
  f32x4 acc[4][4];
#pragma unroll
  for (int i = 0; i < 4; i++)
#pragma unroll
    for (int j = 0; j < 4; j++) acc[i][j] = z4;
  const u16* Ag = A + (size_t)m0 * K;
  const u16* Bg = Bt + (size_t)n0 * K;
  auto stage = [&](int kt, int bufi) {
#pragma unroll
    for (int i = 0; i < 4; i++) {
      const int row = i * 64 + tr;
      const int col = tc8 ^ ((row & 7) << 3);  // pre-swizzled source (u16)
      gload_lds16(Ag + (size_t)row * K + kt * 64 + col,
                  Abuf + bufi * 16384 + i * 4096 + w * 512);
    }
#pragma unroll
    for (int i = 0; i < 2; i++) {
      const int row = i * 64 + tr;
      const int col = tc8 ^ ((row & 7) << 3);
      gload_lds16(Bg + (size_t)row * K + kt * 64 + col,
                  Bbuf + bufi * 8192 + i * 4096 + w * 512);
    }
  };
  const int nt = K >> 6;  // 32
  stage(0, 0);
  stage(1, 1);
  int cur = 0;
#pragma unroll 1
  for (int kt = 0; kt < nt; kt++) {
    if (kt + 2 < nt) {
      int nb = cur + 2; if (nb >= 3) nb -= 3;
      stage(kt + 2, nb);
      asm volatile("s_waitcnt vmcnt(12)" ::: "memory");  // kt done; kt+1,kt+2 in flight
    } else if (kt + 1 < nt) {
      asm volatile("s_waitcnt vmcnt(6)" ::: "memory");   // kt done; kt+1 in flight
    } else {
      asm volatile("s_waitcnt vmcnt(0)" ::: "memory");
    }
    __builtin_amdgcn_s_barrier();
    const u16* Ab = Abuf + cur * 16384;
    const u16* Bb = Bbuf + cur * 8192;
    s16x8 af[4][2], bff[4][2];
#pragma unroll
    for (int sm = 0; sm < 4; sm++) {
      const int row = wr * 64 + sm * 16 + lm;
#pragma unroll
      for (int kk = 0; kk < 2; kk++)
        af[sm][kk] = *(const s16x8*)&Ab[row * 64 +
            ((((kk << 6) | (lq << 4)) ^ ((row & 7) << 4)) >> 1)];
    }
#pragma unroll
    for (int sn = 0; sn < 4; sn++) {
      const int row = wc * 64 + sn * 16 + lm;
#pragma unroll
      for (int kk = 0; kk < 2; kk++)
        bff[sn][kk] = *(const s16x8*)&Bb[row * 64 +
            ((((kk << 6) | (lq << 4)) ^ ((row & 7) << 4)) >> 1)];
    }
#pragma unroll
    for (int kk = 0; kk < 2; kk++)
#pragma unroll
      for (int sm = 0; sm < 4; sm++)
#pragma unroll
        for (int sn = 0; sn < 4; sn++)
          acc[sm][sn] = __builtin_amdgcn_mfma_f32_16x16x32_bf16(
              af[sm][kk], bff[sn][kk], acc[sm][sn], 0, 0, 0);
    asm volatile("s_waitcnt lgkmcnt(0)" ::: "memory");
    __builtin_amdgcn_s_barrier();
    cur = (cur == 2) ? 0 : cur + 1;
  }
#pragma unroll
  for (int sm = 0; sm < 4; sm++)
#pragma unroll
    for (int sn = 0; sn < 4; sn++)
#pragma unroll
      for (int r = 0; r < 4; r++) {
        const int row = m0 + wr * 64 + sm * 16 + lq * 4 + r;
        const int col = n0 + wc * 64 + sn * 16 + lm;
        float v = acc[sm][sn][r] + 0.01f * bfu2f(addsrc[(size_t)row * Nst + col]);
        Cf[(size_t)row * Nst + col] = v;
      }
}

// ---------------------------------------------------------------- flash attention: 64 KB LDS, 2 blocks/CU
// 512 blocks x 512 threads. bid: half=bid>>8, idx=bid&255, set=idx&7
// (b*4+kvh), rest=idx>>3, j0=rest>>1, hp=rest&1; j = half ? 31-j0 : j0.
// Complementary-j: bid and bid+256 (round-robin same CU) pair to 33 units;
// all 512 blocks co-resident (2/CU) -> no dispatch tail. Wave w: head
// h = kvh*4+hp*2+(w&1); chunk c = 2j+((w>>1)&1); row-half mh = w>>2.
// K dbuf + V single-buffer: per kt issue V(kt)+K(kt+1); vmcnt(4); bar;
// QK/exp/P; vmcnt(2); bar; PV; bar (V reuse guard).
__global__ __launch_bounds__(512) void flash_attn_wave(
    const u16* __restrict__ Q, const u16* __restrict__ Kx,
    const u16* __restrict__ Vt, u16* __restrict__ AO) {
  __shared__ u16 Klds[2][64 * 128];   // [buf][key][d], 2x16 KB, swizzled contents
  __shared__ u16 Vlds[128 * 64];      // [d][key], 16 KB, swizzled contents
  __shared__ u16 Pl[8][16][64];       // per-wave P tile (packed), 16 KB
  const int bid = blockIdx.x;
  const int half = bid >> 8;
  const int idx = bid & 255;
  const int set = idx & 7;
  const int b = set >> 2, kvh = set & 3;
  const int rest = idx >> 3;
  const int j0 = rest >> 1, hp = rest & 1;
  const int j = half ? (31 - j0) : j0;
  const int t = threadIdx.x, w = t >> 6, l = t & 63, lm = l & 15, lq = l >> 4;
  const int h = kvh * 4 + hp * 2 + (w & 1);
  const int cs = (w >> 1) & 1, mh = w >> 2;
  const float scale2 = 0.127517827f;   // (1/sqrt(128)) * log2(e)
  const u16* Kbase = Kx + (size_t)(b * 2048) * 512 + kvh * 128;
  const u16* Vbase = Vt + (size_t)(b * 512 + kvh * 128) * 2048;
  const f32x4 z4 = {0.f, 0.f, 0.f, 0.f};

  auto stageK = [&](int kt, int bufi) {
    const int key0 = kt * 64;
#pragma unroll
    for (int r = 0; r < 2; r++) {
      const int row = r * 32 + w * 4 + (l >> 4);     // key row 0..63
      const int scb = ((l & 15) * 16) ^ ((row & 7) << 4);
      gload_lds16(Kbase + (size_t)(key0 + row) * 512 + (scb >> 1),
                  &Klds[bufi][r * 4096 + w * 512]);
    }
  };
  auto stageV = [&](int kt) {
    const int key0 = kt * 64;
#pragma unroll
    for (int r = 0; r < 2; r++) {
      const int row = r * 64 + w * 8 + (l >> 3);     // d row 0..127
      const int scb = ((l & 7) * 16) ^ ((row & 7) << 4);
      gload_lds16(Vbase + (size_t)row * 2048 + key0 + (scb >> 1),
                  &Vlds[r * 4096 + w * 512]);
    }
  };

  const int c = 2 * j + cs;
  const int base = c * 32;
  int cur = 0;
  stageK(0, 0);
  // Q fragment for this wave's 16 rows (4 global loads; drained with the
  // prologue K by round 0's vmcnt(4))
  s16x8 qf[4];
#pragma unroll
  for (int kk = 0; kk < 4; kk++)
    qf[kk] = *(const s16x8*)(Q + ((size_t)(b * 2048 + base + mh * 16 + lm)) * 2048 +
                             h * 128 + kk * 32 + lq * 8);
  f32x4 oacc[8];
#pragma unroll
  for (int e = 0; e < 8; e++) oacc[e] = z4;
  float lsum[4] = {0.f, 0.f, 0.f, 0.f};
#pragma unroll 1
  for (int kt = 0; kt <= j; kt++) {
    const int key0 = kt * 64;
    stageV(kt);
    if (kt < j) {
      stageK(kt + 1, cur ^ 1);
      asm volatile("s_waitcnt vmcnt(4)" ::: "memory");  // K(kt)+qf drained; V+K' in flight
    } else {
      asm volatile("s_waitcnt vmcnt(2)" ::: "memory");  // K(kt)+qf drained; V in flight
    }
    __builtin_amdgcn_s_barrier();
    const char* KB = (const char*)&Klds[cur][0];
    // ---- QK^T for this wave's 16 rows x 64 keys
    s16x8 kf[4][4];
#pragma unroll
    for (int nst = 0; nst < 4; nst++)
#pragma unroll
      for (int kk = 0; kk < 4; kk++) {
        const int row = nst * 16 + lm;
        const int cb = (kk * 64 + lq * 16) ^ ((row & 7) << 4);
        kf[nst][kk] = *(const s16x8*)(KB + row * 256 + cb);
      }
    f32x4 sacc[4];
#pragma unroll
    for (int i = 0; i < 4; i++) sacc[i] = z4;
    __builtin_amdgcn_s_setprio(1);
#pragma unroll
    for (int nst = 0; nst < 4; nst++)
#pragma unroll
      for (int kk = 0; kk < 4; kk++)
        sacc[nst] = __builtin_amdgcn_mfma_f32_16x16x32_bf16(
            qf[kk], kf[nst][kk], sacc[nst], 0, 0, 0);
    __builtin_amdgcn_s_setprio(0);
    // exp (all tiles); mask only on the diagonal tile (uniform branch)
    float pv[4][4];
#pragma unroll
    for (int r = 0; r < 4; r++)
#pragma unroll
      for (int nst = 0; nst < 4; nst++)
        pv[r][nst] = __builtin_amdgcn_exp2f(sacc[nst][r] * scale2);
    if (kt == j) {
#pragma unroll
      for (int r = 0; r < 4; r++) {
        const int qrow = base + mh * 16 + lq * 4 + r;
#pragma unroll
        for (int nst = 0; nst < 4; nst++)
          if (key0 + nst * 16 + lm > qrow) pv[r][nst] = 0.f;
      }
    }
#pragma unroll
    for (int r = 0; r < 4; r++) {
      lsum[r] += (pv[r][0] + pv[r][1]) + (pv[r][2] + pv[r][3]);
      u32 p01, p23;
      asm("v_cvt_pk_bf16_f32 %0, %1, %2" : "=v"(p01) : "v"(pv[r][0]), "v"(pv[r][1]));
      asm("v_cvt_pk_bf16_f32 %0, %1, %2" : "=v"(p23) : "v"(pv[r][2]), "v"(pv[r][3]));
      u16* prow = &Pl[w][lq * 4 + r][lm];
      prow[0]  = (u16)p01;
      prow[16] = (u16)(p01 >> 16);
      prow[32] = (u16)p23;
      prow[48] = (u16)(p23 >> 16);
    }
    // ---- wait own V loads, then barrier so ALL waves' V is resident
    if (kt < j) {
      asm volatile("s_waitcnt vmcnt(2)" ::: "memory");  // V drained; K(kt+1) in flight
    } else {
      asm volatile("s_waitcnt vmcnt(0)" ::: "memory");
    }
    __builtin_amdgcn_s_barrier();
    // ---- PV
    const char* VB = (const char*)&Vlds[0];
    s16x8 vf[8][2];
#pragma unroll
    for (int et = 0; et < 8; et++)
#pragma unroll
      for (int kc = 0; kc < 2; kc++) {
        const int row = et * 16 + lm;
        const int cb = (kc * 64 + lq * 16) ^ ((row & 7) << 4);
        vf[et][kc] = *(const s16x8*)(VB + row * 128 + cb);
      }
    s16x8 pf[2];
#pragma unroll
    for (int kc = 0; kc < 2; kc++)
      pf[kc] = *(const s16x8*)&Pl[w][lm][kc * 32 + lq * 8];
    __builtin_amdgcn_s_setprio(1);
#pragma unroll
    for (int et = 0; et < 8; et++)
#pragma unroll
      for (int kc = 0; kc < 2; kc++)
        oacc[et] = __builtin_amdgcn_mfma_f32_16x16x32_bf16(
            pf[kc], vf[et][kc], oacc[et], 0, 0, 0);
    __builtin_amdgcn_s_setprio(0);
    asm volatile("s_waitcnt lgkmcnt(0)" ::: "memory");
    __builtin_amdgcn_s_barrier();    // V reuse guard: all PV reads done
    cur ^= 1;
  }
  // ---- normalize + store
#pragma unroll
  for (int r = 0; r < 4; r++) {
#pragma unroll
    for (int off = 1; off < 16; off <<= 1)
      lsum[r] += __shfl_xor(lsum[r], off, 64);
  }
#pragma unroll
  for (int r = 0; r < 4; r++) {
    const float inv = 1.f / lsum[r];
    const int row = base + mh * 16 + lq * 4 + r;
    u16* op = AO + ((size_t)(b * 2048 + row)) * 2048 + h * 128;
#pragma unroll
    for (int et = 0; et < 8; et++) op[et * 16 + lm] = f2bfu(oacc[et][r] * inv);
  }
}

// ---------------------------------------------------------------- FLA: per-32-chunk gates + contribution
__global__ __launch_bounds__(256) void fla_contrib32(
    const u16* __restrict__ Kx, const u16* __restrict__ Vt,
    u16* __restrict__ Gg, u16* __restrict__ Ktg, u16* __restrict__ MT,
    float* __restrict__ Lam) {
  __shared__ float gl[32][132];
  __shared__ float kl[32][132];
  __shared__ float ktl[32][132];
  __shared__ u16 khT[128][40];
  const int c = blockIdx.x, kvh = blockIdx.y, b = blockIdx.z;
  const int bk = b * 4 + kvh;
  const int t = threadIdx.x;
  const size_t cb = (size_t)bk * 64 + c;
  {
    const int r = t >> 3, c0 = (t & 7) * 16;
    const u16* kp = Kx + ((size_t)(b * 2048 + c * 32 + r)) * 512 + kvh * 128 + c0;
#pragma unroll
    for (int i = 0; i < 2; i++) {
      float kv[8];
      bf8_to_f(*(const s16x8*)(kp + i * 8), kv);
#pragma unroll
      for (int j = 0; j < 8; j++) {
        kl[r][c0 + i * 8 + j] = kv[j];
        gl[r][c0 + i * 8 + j] = 1.f / (1.f + __expf(-kv[j]));
      }
    }
  }
  __syncthreads();
  if (t < 128) {  // one thread per d: cumprod + ktilde + khat^T
    float G = 1.f;
#pragma unroll
    for (int s = 0; s < 32; s++) {
      G *= gl[s][t];
      gl[s][t] = G;
      ktl[s][t] = kl[s][t] / G;
    }
    Lam[cb * 128 + t] = G;
    const float lam = G;
#pragma unroll
    for (int s = 0; s < 32; s++) khT[t][s] = f2bfu(ktl[s][t] * lam);
  }
  __syncthreads();
  {
    const int r = t >> 3, c0 = (t & 7) * 16;
    u16* gp = Gg + cb * 4096 + r * 128 + c0;
    u16* kp = Ktg + cb * 4096 + r * 128 + c0;
#pragma unroll
    for (int i = 0; i < 2; i++) {
      f32x4 a = *(f32x4*)&gl[r][c0 + i * 8];
      f32x4 b2 = *(f32x4*)&gl[r][c0 + i * 8 + 4];
      *(s16x8*)(gp + i * 8) = pack_bf8(a, b2);
      a = *(f32x4*)&ktl[r][c0 + i * 8];
      b2 = *(f32x4*)&ktl[r][c0 + i * 8 + 4];
      *(s16x8*)(kp + i * 8) = pack_bf8(a, b2);
    }
  }
  const int w = t >> 6, l = t & 63, lm = l & 15, lq = l >> 4;
  const f32x4 z4 = {0.f, 0.f, 0.f, 0.f};
  f32x4 macc[2][8];
#pragma unroll
  for (int ei = 0; ei < 2; ei++)
#pragma unroll
    for (int dt = 0; dt < 8; dt++) macc[ei][dt] = z4;
  s16x8 vtf[2];
#pragma unroll
  for (int ei = 0; ei < 2; ei++) {
    const int et = w * 2 + ei;
    vtf[ei] = *(const s16x8*)(Vt + ((size_t)(b * 512 + kvh * 128 + et * 16 + lm)) * 2048 +
                              c * 32 + lq * 8);
  }
#pragma unroll
  for (int dt = 0; dt < 8; dt++) {
    s16x8 kf = *(const s16x8*)&khT[dt * 16 + lm][lq * 8];
#pragma unroll
    for (int ei = 0; ei < 2; ei++)
      macc[ei][dt] = __builtin_amdgcn_mfma_f32_16x16x32_bf16(vtf[ei], kf, macc[ei][dt], 0, 0, 0);
  }
  u16* mp = MT + cb * 16384;
#pragma unroll
  for (int ei = 0; ei < 2; ei++)
#pragma unroll
    for (int dt = 0; dt < 8; dt++)
#pragma unroll
      for (int r = 0; r < 4; r++)
        mp[(size_t)((w * 2 + ei) * 16 + lq * 4 + r) * 128 + dt * 16 + lm] =
            f2bfu(macc[ei][dt][r]);
}

// ---------------------------------------------------------------- FLA prefix: parallel over (bk,e,d), depth-2 prefetch
__global__ __launch_bounds__(256) void fla_prefix32(
    const u16* __restrict__ MT, const float* __restrict__ Lam, u16* __restrict__ SwsT) {
  const int eg = blockIdx.x, bk = blockIdx.y;
  const int t = threadIdx.x;
  const int e = eg * 4 + (t >> 6), d0 = (t & 63) * 2;
  const size_t cb0 = (size_t)bk * 64;
  const u16* mp = MT + cb0 * 16384 + e * 128 + d0;
  const float* lp = Lam + cb0 * 128 + d0;
  u16* sp = SwsT + cb0 * 16384 + e * 128 + d0;
  float s0 = 0.f, s1 = 0.f;
  u32 ma = *(const u32*)mp;
  u32 mb = *(const u32*)(mp + 16384);
  f32x2 la = *(const f32x2*)lp;
  f32x2 lb = *(const f32x2*)(lp + 128);
#pragma unroll 1
  for (int c = 0; c < 64; c += 2) {
    u32 na = 0, nb = 0;
    f32x2 nla = {0.f, 0.f}, nlb = {0.f, 0.f};
    if (c + 2 < 64) {
      na = *(const u32*)(mp + (size_t)(c + 2) * 16384);
      nla = *(const f32x2*)(lp + (size_t)(c + 2) * 128);
      nb = *(const u32*)(mp + (size_t)(c + 3) * 16384);
      nlb = *(const f32x2*)(lp + (size_t)(c + 3) * 128);
    }
    *(u32*)(sp + (size_t)c * 16384) = (u32)f2bfu(s0) | ((u32)f2bfu(s1) << 16);
    s0 = s0 * la[0] + bfu2f((u16)(ma & 0xffffu));
    s1 = s1 * la[1] + bfu2f((u16)(ma >> 16));
    *(u32*)(sp + (size_t)(c + 1) * 16384) = (u32)f2bfu(s0) | ((u32)f2bfu(s1) << 16);
    s0 = s0 * lb[0] + bfu2f((u16)(mb & 0xffffu));
    s1 = s1 * lb[1] + bfu2f((u16)(mb >> 16));
    ma = na; mb = nb; la = nla; lb = nlb;
  }
}

// ---------------------------------------------------------------- FLA output: O = scale*(q~ S0 + tril(q~ k~^T) v)
__global__ __launch_bounds__(256) void fla_output_mfma(
    const u16* __restrict__ Q, const u16* __restrict__ Gg, const u16* __restrict__ Ktg,
    const u16* __restrict__ SwsT, const u16* __restrict__ Vt, u16* __restrict__ Fla) {
  __shared__ u16 Pl[4][2][16][40];
  const int c = blockIdx.x, h = blockIdx.y, b = blockIdx.z;
  const int kvh = h >> 2, bk = b * 4 + kvh;
  const int t = threadIdx.x, w = t >> 6, l = t & 63, lm = l & 15, lq = l >> 4;
  const float scale = 0.0883883476483184f;
  const size_t cb = (size_t)bk * 64 + c;
  const f32x4 z4 = {0.f, 0.f, 0.f, 0.f};
  s16x8 qgf[2][4];
#pragma unroll
  for (int m = 0; m < 2; m++)
#pragma unroll
    for (int kk = 0; kk < 4; kk++) {
      float qv[8], gv[8];
      bf8_to_f(*(const s16x8*)(Q + ((size_t)(b * 2048 + c * 32 + m * 16 + lm)) * 2048 +
                               h * 128 + kk * 32 + lq * 8), qv);
      bf8_to_f(*(const s16x8*)(Gg + cb * 4096 + (m * 16 + lm) * 128 + kk * 32 + lq * 8), gv);
      f32x4 a, b2;
#pragma unroll
      for (int j = 0; j < 4; j++) { a[j] = qv[j] * gv[j]; b2[j] = qv[4 + j] * gv[4 + j]; }
      qgf[m][kk] = pack_bf8(a, b2);
    }
  f32x4 sacc[2][2];
#pragma unroll
  for (int m = 0; m < 2; m++)
#pragma unroll
    for (int st = 0; st < 2; st++) sacc[m][st] = z4;
#pragma unroll
  for (int st = 0; st < 2; st++)
#pragma unroll
    for (int kk = 0; kk < 4; kk++) {
      s16x8 ktf = *(const s16x8*)(Ktg + cb * 4096 + (st * 16 + lm) * 128 + kk * 32 + lq * 8);
#pragma unroll
      for (int m = 0; m < 2; m++)
        sacc[m][st] = __builtin_amdgcn_mfma_f32_16x16x32_bf16(qgf[m][kk], ktf, sacc[m][st], 0, 0, 0);
    }
#pragma unroll
  for (int m = 0; m < 2; m++)
#pragma unroll
    for (int st = 0; st < 2; st++)
#pragma unroll
      for (int r = 0; r < 4; r++) {
        const int trow = m * 16 + lq * 4 + r;
        const int scol = st * 16 + lm;
        Pl[w][m][lq * 4 + r][st * 16 + lm] = f2bfu(scol <= trow ? sacc[m][st][r] : 0.f);
      }
  s16x8 pf[2];
#pragma unroll
  for (int m = 0; m < 2; m++) pf[m] = *(const s16x8*)&Pl[w][m][lm][lq * 8];
  f32x4 oacc[2][2];
#pragma unroll
  for (int m = 0; m < 2; m++)
#pragma unroll
    for (int ei = 0; ei < 2; ei++) oacc[m][ei] = z4;
#pragma unroll
  for (int ei = 0; ei < 2; ei++) {
    const int et = w * 2 + ei;
    s16x8 vtf = *(const s16x8*)(Vt + ((size_t)(b * 512 + kvh * 128 + et * 16 + lm)) * 2048 +
                                c * 32 + lq * 8);
#pragma unroll
    for (int m = 0; m < 2; m++)
      oacc[m][ei] = __builtin_amdgcn_mfma_f32_16x16x32_bf16(pf[m], vtf, oacc[m][ei], 0, 0, 0);
#pragma unroll
    for (int kk = 0; kk < 4; kk++) {
      s16x8 s0f = *(const s16x8*)(SwsT + cb * 16384 + (et * 16 + lm) * 128 + kk * 32 + lq * 8);
#pragma unroll
      for (int m = 0; m < 2; m++)
        oacc[m][ei] = __builtin_amdgcn_mfma_f32_16x16x32_bf16(qgf[m][kk], s0f, oacc[m][ei], 0, 0, 0);
    }
  }
#pragma unroll
  for (int m = 0; m < 2; m++)
#pragma unroll
    for (int ei = 0; ei < 2; ei++)
#pragma unroll
      for (int r = 0; r < 4; r++)
        Fla[((size_t)(b * 2048 + c * 32 + m * 16 + lq * 4 + r)) * 2048 + h * 128 +
            (w * 2 + ei) * 16 + lm] = f2bfu(scale * oacc[m][ei][r]);
}

// ---------------------------------------------------------------- launch
extern "C" void kernel_launch(void* const* d_in, const int* in_sizes, int n_in,
                              void* d_out, int out_size, void* d_ws, size_t ws_size,
                              hipStream_t stream) {
  const float* X  = (const float*)d_in[0];
  const float* Wq = (const float*)d_in[1];
  const float* Wk = (const float*)d_in[2];
  const float* Wv = (const float*)d_in[3];
  const float* Wo = (const float*)d_in[4];
  float* out = (float*)d_out;

  char* ws = (char*)d_ws;
  size_t off = 0;
  auto alloc = [&](size_t bytes) { void* p = ws + off; off += (bytes + 255) & ~(size_t)255; return p; };
  u16* WoT = (u16*)alloc(2048ull * 2048 * 2);     // 8 MB, live to end
  u16* Qb  = (u16*)alloc(4096ull * 2048 * 2);     // 16 MB
  u16* Kb  = (u16*)alloc(4096ull * 512 * 2);      // 4 MB
  u16* Vb  = (u16*)alloc(4096ull * 512 * 2);      // 4 MB
  u16* Vtb = (u16*)alloc(2ull * 512 * 2048 * 2);  // 4 MB
  u16* Fla = (u16*)alloc(4096ull * 2048 * 2);     // 16 MB
  // time-shared 16 MB region: Xb (until KV proj) -> MT (contrib..prefix) -> AO (flash..end)
  u16* SH16 = (u16*)alloc(4096ull * 2048 * 2);
  u16* Xb = SH16;
  u16* MT = SH16;
  u16* AO = SH16;
  // time-shared scratch: WqT/WkT/WvT early; G/ktilde/SwsT/Lam after projections
  char* BIG = (char*)alloc(26ull * 1024 * 1024);
  u16* WqT = (u16*)BIG;                            // 8 MB
  u16* WkT = (u16*)(BIG + 8ull * 1024 * 1024);     // 2 MB
  u16* WvT = (u16*)(BIG + 10ull * 1024 * 1024);    // 2 MB
  u16* Gg   = (u16*)BIG;                           // 4 MB
  u16* Ktg  = (u16*)(BIG + 4194304ull);            // 4 MB
  u16* SwsT = (u16*)(BIG + 8388608ull);            // 16.78 MB
  float* Lam = (float*)(BIG + 8388608ull + 16777216ull);  // 256 KB
  (void)ws_size; (void)in_sizes; (void)n_in; (void)out_size;

  dim3 blk(256);
  f32_to_bf16<<<dim3(4096), blk, 0, stream>>>(X, Xb, 4096 * 2048 / 8);
  transpose_w4<<<dim3(10240), blk, 0, stream>>>(Wq, Wk, Wv, Wo, WqT, WkT, WvT, WoT);

  gemm_qkv<<<dim3(24, 32), blk, 0, stream>>>(Xb, WqT, WkT, WvT, Qb, Kb, Vb);

  transpose_bf16v<<<dim3(16, 64, 2), blk, 0, stream>>>(Vb, Vtb);

  // ---- FLA branch (MT overwrites dead Xb; AO reuses region after prefix consumes MT)
  fla_contrib32<<<dim3(64, 4, 2), blk, 0, stream>>>(Kb, Vtb, Gg, Ktg, MT, Lam);
  fla_prefix32<<<dim3(32, 8), blk, 0, stream>>>(MT, Lam, SwsT);
  fla_output_mfma<<<dim3(64, 16, 2), blk, 0, stream>>>(Qb, Gg, Ktg, SwsT, Vtb, Fla);

  // ---- base attention (AO overwrites dead MT)
  flash_attn_wave<<<dim3(512), dim3(512), 0, stream>>>(Qb, Kb, Vtb, AO);

  gemm_out2<<<dim3(16, 16), dim3(512), 0, stream>>>(AO, WoT, out, Fla);
}